// Round 2
// baseline (429.320 us; speedup 1.0000x reference)
//
#include <hip/hip_runtime.h>
#include <math.h>

#define B_ 8
#define S_ 1024
#define D_ 768
#define H_ 8
#define DH_ 96
#define DFF_ 3072
#define NTOK (B_*S_)
#define QKVW 2304            // fused q|k|v width
#define EPS_ 1e-5f

typedef __attribute__((ext_vector_type(4))) float f4;
typedef __attribute__((ext_vector_type(4))) int i4;
typedef __attribute__((ext_vector_type(8))) __bf16 bf16x8;
typedef __attribute__((ext_vector_type(4))) unsigned short us4;
typedef __attribute__((ext_vector_type(8))) unsigned short us8;

static __device__ __forceinline__ unsigned short f2bf(float f) {
    unsigned int u = __builtin_bit_cast(unsigned int, f);
    u += 0x7fffu + ((u >> 16) & 1u);
    return (unsigned short)(u >> 16);
}
static __device__ __forceinline__ float bf2f(unsigned short u) {
    unsigned int x = ((unsigned int)u) << 16;
    return __builtin_bit_cast(float, x);
}

#define GLOBAL_LOAD_LDS16(g, l) \
    __builtin_amdgcn_global_load_lds((const __attribute__((address_space(1))) unsigned int*)(g), \
                                     (__attribute__((address_space(3))) unsigned int*)(l), 16, 0, 0)

// ---------------------------------------------------------------------------
// SLN: out_bf16 = bf16( x * (gamma * LayerNorm(h) + beta) ); optional x copy (fp32)
// ---------------------------------------------------------------------------
__global__ __launch_bounds__(192) void sln_kernel(
    const float* __restrict__ h, const float* __restrict__ x,
    const float* __restrict__ gamma, const float* __restrict__ beta,
    const float* __restrict__ w, const float* __restrict__ bvec,
    unsigned short* __restrict__ out_bf, float* __restrict__ xcopy)
{
    int row = blockIdx.x;
    int t = threadIdx.x;
    const float4* h4 = (const float4*)(h + (size_t)row * D_);
    const float4* x4 = (const float4*)(x + (size_t)row * D_);
    float4 hv = h4[t];
    float s  = hv.x + hv.y + hv.z + hv.w;
    float ss = hv.x*hv.x + hv.y*hv.y + hv.z*hv.z + hv.w*hv.w;
    #pragma unroll
    for (int off = 32; off > 0; off >>= 1) {
        s  += __shfl_down(s, off);
        ss += __shfl_down(ss, off);
    }
    __shared__ float red[2][3];
    int wid = t >> 6;
    if ((t & 63) == 0) { red[0][wid] = s; red[1][wid] = ss; }
    __syncthreads();
    float sum   = red[0][0] + red[0][1] + red[0][2];
    float sumsq = red[1][0] + red[1][1] + red[1][2];
    float mu  = sum * (1.0f / D_);
    float var = sumsq * (1.0f / D_) - mu * mu;
    float rstd = rsqrtf(var + EPS_);
    float g = gamma[0], be = beta[0];
    float4 wv = ((const float4*)w)[t];
    float4 bv = ((const float4*)bvec)[t];
    float4 xv = x4[t];
    us4 o;
    o.x = f2bf(xv.x * (g * ((hv.x - mu) * rstd * wv.x + bv.x) + be));
    o.y = f2bf(xv.y * (g * ((hv.y - mu) * rstd * wv.y + bv.y) + be));
    o.z = f2bf(xv.z * (g * ((hv.z - mu) * rstd * wv.z + bv.z) + be));
    o.w = f2bf(xv.w * (g * ((hv.w - mu) * rstd * wv.w + bv.w) + be));
    *(us4*)(out_bf + (size_t)row * D_ + t * 4) = o;
    if (xcopy) ((float4*)(xcopy + (size_t)row * D_))[t] = xv;
}

// ---------------------------------------------------------------------------
// Merged weight prep: all 6 transposes (fp32->bf16, [K][N]->[N][K]) + bias concat
// Wk and bk are pre-scaled by -2 so the attention QK^T MFMA emits -2*q.k
// directly (L2-distance expansion); norms_kernel compensates k2 by *0.25.
// ---------------------------------------------------------------------------
__global__ __launch_bounds__(256) void prep_all_kernel(
    const float* __restrict__ Wq, const float* __restrict__ Wk,
    const float* __restrict__ Wv, const float* __restrict__ Wo,
    const float* __restrict__ W1, const float* __restrict__ W2,
    const float* __restrict__ bq, const float* __restrict__ bk, const float* __restrict__ bv,
    unsigned short* __restrict__ Wqkvt, unsigned short* __restrict__ Wot,
    unsigned short* __restrict__ W1t, unsigned short* __restrict__ W2t,
    float* __restrict__ bqkv)
{
    int id = blockIdx.x;
    int tx = threadIdx.x, ty = threadIdx.y;
    if (id >= 6912) {   // bias concat: 9 blocks x 256 threads
        int i = (id - 6912) * 256 + ty * 32 + tx;
        if (i < QKVW) {
            float v = (i < 768) ? bq[i] : (i < 1536) ? -2.f * bk[i - 768] : bv[i - 1536];
            bqkv[i] = v;
        }
        return;
    }
    const float* in; unsigned short* out; int K, N, nbx, rel;
    float scl = 1.f;
    if (id < 1728)      { int m = id / 576; rel = id % 576;
                          in = (m == 0) ? Wq : (m == 1) ? Wk : Wv;
                          if (m == 1) scl = -2.f;
                          out = Wqkvt + (size_t)m * 768 * 768; K = 768; N = 768; nbx = 24; }
    else if (id < 2304) { rel = id - 1728; in = Wo; out = Wot;  K = 768;  N = 768;  nbx = 24; }
    else if (id < 4608) { rel = id - 2304; in = W1; out = W1t;  K = 768;  N = 3072; nbx = 96; }
    else                { rel = id - 4608; in = W2; out = W2t;  K = 3072; N = 768;  nbx = 24; }
    int n0 = (rel % nbx) * 32, k0 = (rel / nbx) * 32;
    __shared__ float tile[32][33];
    #pragma unroll
    for (int r = 0; r < 4; r++)
        tile[ty + r * 8][tx] = in[(size_t)(k0 + ty + r * 8) * N + n0 + tx];
    __syncthreads();
    #pragma unroll
    for (int r = 0; r < 4; r++)
        out[(size_t)(n0 + ty + r * 8) * K + k0 + tx] = f2bf(scl * tile[tx][ty + r * 8]);
}

// ---------------------------------------------------------------------------
// bf16 MFMA GEMM, 128x128 tile, BK=32, double-buffered prefetch (T3 2-phase),
// XOR chunk-swizzled LDS (pre-swizzled global source, linear gload_lds dest).
// ---------------------------------------------------------------------------
template<int OUT_BF16, int RELU>
__global__ __launch_bounds__(256) void gemm_mfma_kernel(
    const unsigned short* __restrict__ A, const unsigned short* __restrict__ Bt,
    const float* __restrict__ bias, const float* __restrict__ resid,
    void* __restrict__ Cout, int M, int N, int K)
{
    __shared__ unsigned short Asm[2][128 * 32];
    __shared__ unsigned short Bsm[2][128 * 32];

    int t = threadIdx.x;
    int lane = t & 63, wv = t >> 6;
    int wm = wv & 1, wn = wv >> 1;
    int l16 = lane & 15, quad = lane >> 4;

    int bm = blockIdx.x * 128;
    int bn = blockIdx.y * 128;

    const unsigned short* Abase = A  + (size_t)bm * K;
    const unsigned short* Bbase = Bt + (size_t)bn * K;

    // staging: fl in [0,1024): row = fl>>2 (4x16B chunks/row of 32 shorts),
    // phys chunk p = fl&3 holds logical chunk l = (fl ^ (fl>>3)) & 3.
    int fl0 = t, fl1 = 256 + t;
    int r0 = fl0 >> 2, lg0 = (fl0 ^ (fl0 >> 3)) & 3;
    int r1 = fl1 >> 2, lg1 = (fl1 ^ (fl1 >> 3)) & 3;

    f4 acc[4][4] = {};   // acc[j][i]: j = weight (col) tile, i = act (row) tile

    // prologue stage
    GLOBAL_LOAD_LDS16(Abase + (size_t)r0 * K + lg0 * 8, &Asm[0][fl0 * 8]);
    GLOBAL_LOAD_LDS16(Abase + (size_t)r1 * K + lg1 * 8, &Asm[0][fl1 * 8]);
    GLOBAL_LOAD_LDS16(Bbase + (size_t)r0 * K + lg0 * 8, &Bsm[0][fl0 * 8]);
    GLOBAL_LOAD_LDS16(Bbase + (size_t)r1 * K + lg1 * 8, &Bsm[0][fl1 * 8]);
    __syncthreads();

    int nk = K >> 5;
    int cur = 0;
    for (int it = 0; it < nk; ++it) {
        if (it + 1 < nk) {
            int k0 = (it + 1) << 5;
            GLOBAL_LOAD_LDS16(Abase + (size_t)r0 * K + k0 + lg0 * 8, &Asm[cur ^ 1][fl0 * 8]);
            GLOBAL_LOAD_LDS16(Abase + (size_t)r1 * K + k0 + lg1 * 8, &Asm[cur ^ 1][fl1 * 8]);
            GLOBAL_LOAD_LDS16(Bbase + (size_t)r0 * K + k0 + lg0 * 8, &Bsm[cur ^ 1][fl0 * 8]);
            GLOBAL_LOAD_LDS16(Bbase + (size_t)r1 * K + k0 + lg1 * 8, &Bsm[cur ^ 1][fl1 * 8]);
        }

        bf16x8 xf[4], wf[4];
        #pragma unroll
        for (int i = 0; i < 4; i++) {
            int m = wm * 64 + i * 16 + l16;
            int p = (quad ^ (m >> 1)) & 3;
            xf[i] = __builtin_bit_cast(bf16x8, *(const i4*)&Asm[cur][m * 32 + p * 8]);
        }
        #pragma unroll
        for (int j = 0; j < 4; j++) {
            int n = wn * 64 + j * 16 + l16;
            int p = (quad ^ (n >> 1)) & 3;
            wf[j] = __builtin_bit_cast(bf16x8, *(const i4*)&Bsm[cur][n * 32 + p * 8]);
        }
        #pragma unroll
        for (int j = 0; j < 4; j++)
            #pragma unroll
            for (int i = 0; i < 4; i++)
                acc[j][i] = __builtin_amdgcn_mfma_f32_16x16x32_bf16(wf[j], xf[i], acc[j][i], 0, 0, 0);

        __syncthreads();   // drains prefetch (vmcnt) + protects cur buffer reuse
        cur ^= 1;
    }

    #pragma unroll
    for (int i = 0; i < 4; i++) {
        int rowg = bm + wm * 64 + i * 16 + l16;
        #pragma unroll
        for (int j = 0; j < 4; j++) {
            int colg0 = bn + wn * 64 + j * 16 + quad * 4;
            f4 v = acc[j][i];
            f4 b4 = *(const f4*)&bias[colg0];
            v += b4;
            if (RELU) {
                #pragma unroll
                for (int r = 0; r < 4; r++) v[r] = fmaxf(v[r], 0.f);
            }
            if (resid) {
                f4 r4 = *(const f4*)&resid[(size_t)rowg * N + colg0];
                v += r4;
            }
            if (OUT_BF16) {
                us4 o;
                o.x = f2bf(v[0]); o.y = f2bf(v[1]); o.z = f2bf(v[2]); o.w = f2bf(v[3]);
                *(us4*)((unsigned short*)Cout + (size_t)rowg * N + colg0) = o;
            } else {
                *(f4*)((float*)Cout + (size_t)rowg * N + colg0) = v;
            }
        }
    }
}

// ---------------------------------------------------------------------------
// bf16 MFMA GEMM, 128x64 tile, BK=64, double-buffered prefetch + XOR swizzle.
// LDS 48KB -> 3 blocks/CU (matches 768-block grid for N=768 GEMMs).
// ---------------------------------------------------------------------------
template<int OUT_BF16, int RELU>
__global__ __launch_bounds__(256) void gemm_mfma_n64_kernel(
    const unsigned short* __restrict__ A, const unsigned short* __restrict__ Bt,
    const float* __restrict__ bias, const float* __restrict__ resid,
    void* __restrict__ Cout, int M, int N, int K)
{
    __shared__ unsigned short Asm[2][128 * 64];
    __shared__ unsigned short Bsm[2][64 * 64];

    int t = threadIdx.x;
    int lane = t & 63, wv = t >> 6;
    int wm = wv & 1, wn = wv >> 1;
    int l16 = lane & 15, quad = lane >> 4;

    int bm = blockIdx.x * 128;
    int bn = blockIdx.y * 64;

    const unsigned short* Abase = A  + (size_t)bm * K;
    const unsigned short* Bbase = Bt + (size_t)bn * K;

    // staging: row = fl>>3 (8x16B chunks/row of 64 shorts),
    // phys chunk p = fl&7 holds logical chunk l = (fl ^ (fl>>3)) & 7.
    int ar[4], alg[4], br[2], blg[2];
    #pragma unroll
    for (int i = 0; i < 4; i++) {
        int fl = t + i * 256;
        ar[i] = fl >> 3; alg[i] = (fl ^ (fl >> 3)) & 7;
    }
    #pragma unroll
    for (int i = 0; i < 2; i++) {
        int fl = t + i * 256;
        br[i] = fl >> 3; blg[i] = (fl ^ (fl >> 3)) & 7;
    }

    f4 acc[2][4] = {};

    // prologue stage (buffer 0, k=0)
    #pragma unroll
    for (int i = 0; i < 4; i++)
        GLOBAL_LOAD_LDS16(Abase + (size_t)ar[i] * K + alg[i] * 8, &Asm[0][(t + i * 256) * 8]);
    #pragma unroll
    for (int i = 0; i < 2; i++)
        GLOBAL_LOAD_LDS16(Bbase + (size_t)br[i] * K + blg[i] * 8, &Bsm[0][(t + i * 256) * 8]);
    __syncthreads();

    int nk = K >> 6;
    int cur = 0;
    for (int it = 0; it < nk; ++it) {
        if (it + 1 < nk) {
            int k0 = (it + 1) << 6;
            #pragma unroll
            for (int i = 0; i < 4; i++)
                GLOBAL_LOAD_LDS16(Abase + (size_t)ar[i] * K + k0 + alg[i] * 8, &Asm[cur ^ 1][(t + i * 256) * 8]);
            #pragma unroll
            for (int i = 0; i < 2; i++)
                GLOBAL_LOAD_LDS16(Bbase + (size_t)br[i] * K + k0 + blg[i] * 8, &Bsm[cur ^ 1][(t + i * 256) * 8]);
        }

        #pragma unroll
        for (int kk = 0; kk < 2; kk++) {
            bf16x8 xf[4], wf[2];
            #pragma unroll
            for (int i = 0; i < 4; i++) {
                int m = wm * 64 + i * 16 + l16;
                int p = ((kk * 4 + quad) ^ (m & 7)) & 7;
                xf[i] = __builtin_bit_cast(bf16x8, *(const i4*)&Asm[cur][m * 64 + p * 8]);
            }
            #pragma unroll
            for (int j = 0; j < 2; j++) {
                int n = wn * 32 + j * 16 + l16;
                int p = ((kk * 4 + quad) ^ (n & 7)) & 7;
                wf[j] = __builtin_bit_cast(bf16x8, *(const i4*)&Bsm[cur][n * 64 + p * 8]);
            }
            #pragma unroll
            for (int j = 0; j < 2; j++)
                #pragma unroll
                for (int i = 0; i < 4; i++)
                    acc[j][i] = __builtin_amdgcn_mfma_f32_16x16x32_bf16(wf[j], xf[i], acc[j][i], 0, 0, 0);
        }

        __syncthreads();   // drains prefetch + protects cur buffer reuse
        cur ^= 1;
    }

    #pragma unroll
    for (int i = 0; i < 4; i++) {
        int rowg = bm + wm * 64 + i * 16 + l16;
        #pragma unroll
        for (int j = 0; j < 2; j++) {
            int colg0 = bn + wn * 32 + j * 16 + quad * 4;
            f4 v = acc[j][i];
            f4 b4 = *(const f4*)&bias[colg0];
            v += b4;
            if (RELU) {
                #pragma unroll
                for (int r = 0; r < 4; r++) v[r] = fmaxf(v[r], 0.f);
            }
            if (resid) {
                f4 r4 = *(const f4*)&resid[(size_t)rowg * N + colg0];
                v += r4;
            }
            if (OUT_BF16) {
                us4 o;
                o.x = f2bf(v[0]); o.y = f2bf(v[1]); o.z = f2bf(v[2]); o.w = f2bf(v[3]);
                *(us4*)((unsigned short*)Cout + (size_t)rowg * N + colg0) = o;
            } else {
                *(f4*)((float*)Cout + (size_t)rowg * N + colg0) = v;
            }
        }
    }
}

// ---------------------------------------------------------------------------
// q2/k2 norms from fused qkv bf16 buffer [NTOK][2304] -> q2g,k2g [B*H*S] fp32
// K in qkvb is pre-scaled by -2 (see prep_all_kernel) -> k2 = 0.25 * sum(K'^2)
// ---------------------------------------------------------------------------
__global__ __launch_bounds__(256) void norms_kernel(
    const unsigned short* __restrict__ qkv, float* __restrict__ q2g, float* __restrict__ k2g)
{
    int row = blockIdx.x;
    int t = threadIdx.x;
    int hh = t >> 5, l32 = t & 31;
    const unsigned short* base = qkv + (size_t)row * QKVW + hh * DH_ + l32 * 3;
    float qs = 0.f, ks = 0.f;
    #pragma unroll
    for (int e = 0; e < 3; e++) {
        float qv = bf2f(base[e]);
        float kv = bf2f(base[768 + e]);
        qs += qv * qv; ks += kv * kv;
    }
    #pragma unroll
    for (int off = 16; off > 0; off >>= 1) {
        qs += __shfl_xor(qs, off, 32);
        ks += __shfl_xor(ks, off, 32);
    }
    if (l32 == 0) {
        int b = row >> 10, s = row & 1023;
        int idx = (b * H_ + hh) * S_ + s;
        q2g[idx] = qs; k2g[idx] = ks * 0.25f;
    }
}

// ---------------------------------------------------------------------------
// V transpose into padded tiles: qkv V-part -> vt[(bh*16+kt)] tile of [96][72] bf16
// ---------------------------------------------------------------------------
__global__ __launch_bounds__(256) void vtrans_kernel(
    const unsigned short* __restrict__ qkv, unsigned short* __restrict__ vt)
{
    __shared__ unsigned short Vl[64][100];
    int blk = blockIdx.x;          // bh*16 + kt
    int bh = blk >> 4, kt = blk & 15;
    int b = bh >> 3, hh = bh & 7;
    int t = threadIdx.x;
    int key = t >> 2, qc = t & 3;
    const unsigned short* src = qkv + ((size_t)(b * S_ + kt * 64 + key)) * QKVW + 1536 + hh * DH_;
    #pragma unroll
    for (int i = 0; i < 3; i++) {
        int chunk = qc + i * 4;            // 0..11, 8 shorts each
        us8 v = *(const us8*)(src + chunk * 8);
        #pragma unroll
        for (int e = 0; e < 8; e++) Vl[key][chunk * 8 + e] = v[e];
    }
    __syncthreads();
    unsigned short* dst = vt + (size_t)blk * 7168;
    #pragma unroll
    for (int r = 0; r < 3; r++) {
        int c = r * 256 + t;               // 0..767
        int vd = c >> 3, kc = c & 7;
        us8 o;
        #pragma unroll
        for (int j = 0; j < 8; j++) o[j] = Vl[kc * 8 + j][vd];
        *(us8*)(dst + vd * 72 + kc * 8) = o;
    }
}

// ---------------------------------------------------------------------------
// MFMA flash attention with L2 distances. K is pre-scaled by -2 and q2+k2 is
// the MFMA C-initializer, so the QK^T MFMA emits d2 = q2+k2-2qk directly.
// K LDS is chunk-major [12][64 keys][8] (conflict-free reads, linear
// global_load_lds dest via pre-swizzled global source). XCD swizzle keeps all
// 16 q-tiles of one head (and one batch) on one XCD (K+V ~3.3MB < 4MB L2).
// ---------------------------------------------------------------------------
__global__ __launch_bounds__(256, 4) void attn_mfma_kernel(
    const unsigned short* __restrict__ qkv,
    const unsigned short* __restrict__ vt,
    const float* __restrict__ q2g, const float* __restrict__ k2g,
    unsigned short* __restrict__ outb)
{
    __shared__ unsigned short Klds[64 * 96];     // chunk-major: [dc 0..11][key 0..63][8]
    __shared__ unsigned short Vlds[7168];        // [vdim][72]
    __shared__ unsigned short Plds[4][16 * 72];  // per-wave [qrow][key], stride 72

    int t = threadIdx.x;
    int lane = t & 63, w = t >> 6;
    int l16 = lane & 15, quad = lane >> 4;

    // XCD swizzle: bid%8 selects XCD (round-robin dispatch); give each XCD
    // one batch (8 heads x 16 qtiles = 128 blocks).
    int bid = blockIdx.x;
    int slot = bid >> 3;
    int bh = (bid & 7) * 8 + (slot >> 4);
    int qt = slot & 15;
    int b = bh >> 3, hh = bh & 7;

    int qrow0 = qt * 64 + w * 16;

    const unsigned short* qb = qkv + ((size_t)(b * S_ + qrow0)) * QKVW + hh * DH_;
    bf16x8 qf[3];
    #pragma unroll
    for (int d = 0; d < 3; d++)
        qf[d] = __builtin_bit_cast(bf16x8,
            *(const i4*)(qb + (size_t)l16 * QKVW + d * 32 + quad * 8));

    float q2n = q2g[bh * S_ + qrow0 + l16];

    float lsum = 0.f;          // per-lane partial (this lane's keys only)
    f4 Oacc[6] = {};

    const float cexp = 0.14724445f;   // log2(e)/sqrt(96)

    const unsigned short* kgb = qkv + ((size_t)(b * S_)) * QKVW + 768 + hh * DH_;
    const unsigned short* vgb0 = vt + (size_t)(bh * 16) * 7168;
    const float* k2base = k2g + bh * S_;

    for (int it = 0; it < 16; it++) {
        // preload k2 for this key-tile early (hidden under staging+barrier)
        float4 k2f[4];
        #pragma unroll
        for (int kt2 = 0; kt2 < 4; kt2++)
            k2f[kt2] = *(const float4*)(k2base + it * 64 + kt2 * 16 + quad * 4);

        __syncthreads();
        // K staging, chunk-major: LDS linear in c, global source permuted
        #pragma unroll
        for (int r = 0; r < 3; r++) {
            int c = r * 256 + t;
            int key = c & 63, dc = c >> 6;
            GLOBAL_LOAD_LDS16(kgb + ((size_t)(it * 64 + key)) * QKVW + dc * 8, &Klds[c * 8]);
        }
        const unsigned short* vgb = vgb0 + (size_t)it * 7168;
        #pragma unroll
        for (int r = 0; r < 3; r++)
            GLOBAL_LOAD_LDS16(vgb + (r * 256 + t) * 8, &Vlds[(r * 256 + t) * 8]);
        if (t < 128)
            GLOBAL_LOAD_LDS16(vgb + (768 + t) * 8, &Vlds[(768 + t) * 8]);
        __syncthreads();

        // S^T = K' . Q^T + (q2+k2) : C-frag col(l16)=qrow, row(quad*4+r)=key
        const unsigned short* kB = &Klds[quad * 512 + l16 * 8];
        #pragma unroll
        for (int kt2 = 0; kt2 < 4; kt2++) {
            const unsigned short* kp = kB + kt2 * 128;
            bf16x8 kf0 = __builtin_bit_cast(bf16x8, *(const i4*)(kp));
            bf16x8 kf1 = __builtin_bit_cast(bf16x8, *(const i4*)(kp + 2048));
            bf16x8 kf2 = __builtin_bit_cast(bf16x8, *(const i4*)(kp + 4096));
            f4 a = {k2f[kt2].x + q2n, k2f[kt2].y + q2n, k2f[kt2].z + q2n, k2f[kt2].w + q2n};
            a = __builtin_amdgcn_mfma_f32_16x16x32_bf16(kf0, qf[0], a, 0, 0, 0);
            a = __builtin_amdgcn_mfma_f32_16x16x32_bf16(kf1, qf[1], a, 0, 0, 0);
            a = __builtin_amdgcn_mfma_f32_16x16x32_bf16(kf2, qf[2], a, 0, 0, 0);
            // p = exp2(-sqrt(max(d2,0)) * log2e/sqrt(DH)); accumulate l; pack
            #pragma unroll
            for (int r2 = 0; r2 < 4; r2++) {
                float d2 = fmaxf(a[r2], 0.f);
                float p = exp2f(-__builtin_amdgcn_sqrtf(d2) * cexp);
                lsum += p;
                a[r2] = p;
            }
            unsigned int plo, phi;
            asm("v_cvt_pk_bf16_f32 %0, %1, %2" : "=v"(plo) : "v"(a[0]), "v"(a[1]));
            asm("v_cvt_pk_bf16_f32 %0, %1, %2" : "=v"(phi) : "v"(a[2]), "v"(a[3]));
            uint2 pkd; pkd.x = plo; pkd.y = phi;
            *(uint2*)&Plds[w][l16 * 72 + kt2 * 16 + quad * 4] = pkd;
        }
        // O += P . V (no rescale needed: fixed shift)
        bf16x8 pa0 = __builtin_bit_cast(bf16x8, *(const i4*)&Plds[w][l16 * 72 + quad * 8]);
        bf16x8 pa1 = __builtin_bit_cast(bf16x8, *(const i4*)&Plds[w][l16 * 72 + 32 + quad * 8]);
        #pragma unroll
        for (int vtl = 0; vtl < 6; vtl++) {
            bf16x8 vf0 = __builtin_bit_cast(bf16x8, *(const i4*)&Vlds[(vtl * 16 + l16) * 72 + quad * 8]);
            bf16x8 vf1 = __builtin_bit_cast(bf16x8, *(const i4*)&Vlds[(vtl * 16 + l16) * 72 + 32 + quad * 8]);
            Oacc[vtl] = __builtin_amdgcn_mfma_f32_16x16x32_bf16(pa0, vf0, Oacc[vtl], 0, 0, 0);
            Oacc[vtl] = __builtin_amdgcn_mfma_f32_16x16x32_bf16(pa1, vf1, Oacc[vtl], 0, 0, 0);
        }
    }
    // single deferred l-reduction over the 4 quads
    lsum += __shfl_xor(lsum, 16, 64);
    lsum += __shfl_xor(lsum, 32, 64);
    float inv_l = 1.f / lsum;
    f4 iv;
    #pragma unroll
    for (int r2 = 0; r2 < 4; r2++)
        iv[r2] = __shfl(inv_l, quad * 4 + r2, 64);
    #pragma unroll
    for (int vtl = 0; vtl < 6; vtl++)
        #pragma unroll
        for (int r2 = 0; r2 < 4; r2++) {
            int row = b * S_ + qrow0 + quad * 4 + r2;
            outb[(size_t)row * D_ + hh * DH_ + vtl * 16 + l16] = f2bf(Oacc[vtl][r2] * iv[r2]);
        }
}

// ---------------------------------------------------------------------------
extern "C" void kernel_launch(void* const* d_in, const int* in_sizes, int n_in,
                              void* d_out, int out_size, void* d_ws, size_t ws_size,
                              hipStream_t stream)
{
    const float* h    = (const float*)d_in[0];
    const float* x    = (const float*)d_in[1];
    const float* g1   = (const float*)d_in[2];
    const float* be1  = (const float*)d_in[3];
    const float* ln1w = (const float*)d_in[4];
    const float* ln1b = (const float*)d_in[5];
    const float* g2   = (const float*)d_in[6];
    const float* be2  = (const float*)d_in[7];
    const float* ln2w = (const float*)d_in[8];
    const float* ln2b = (const float*)d_in[9];
    const float* Wq   = (const float*)d_in[10];
    const float* bq   = (const float*)d_in[11];
    const float* Wk   = (const float*)d_in[12];
    const float* bk   = (const float*)d_in[13];
    const float* Wv   = (const float*)d_in[14];
    const float* bv   = (const float*)d_in[15];
    const float* Wo   = (const float*)d_in[16];
    const float* bo   = (const float*)d_in[17];
    const float* W1   = (const float*)d_in[18];
    const float* b1   = (const float*)d_in[19];
    const float* W2   = (const float*)d_in[20];
    const float* b2   = (const float*)d_in[21];

    float* out = (float*)d_out;
    char* wsb = (char*)d_ws;
    const size_t ND = (size_t)NTOK * D_;

    // workspace layout (bytes): persistent region first, dead-pool last so
    // the full-size MLP hidden (50.3 MB bf16) can overlay the dead pool.
    size_t off = 0;
    unsigned short* W1t = (unsigned short*)(wsb + off); off += 4718592;       // [3072][768]
    unsigned short* W2t = (unsigned short*)(wsb + off); off += 4718592;       // [768][3072]
    float* bqkv = (float*)(wsb + off);                  off += 16384;
    float* htmp = (float*)(wsb + off);                  off += ND * 4;        // fp32
    float* q2g  = (float*)(wsb + off);                  off += (size_t)B_ * H_ * S_ * 4;
    float* k2g  = (float*)(wsb + off);                  off += (size_t)B_ * H_ * S_ * 4;
    unsigned short* h2b = (unsigned short*)(wsb + off); off += ND * 2;        // SLN2 out
    // ---- dead pool (all dead before the MLP) ----
    size_t pool0 = off;
    unsigned short* Wqkvt = (unsigned short*)(wsb + off); off += 3538944;     // [2304][768]
    unsigned short* Wot   = (unsigned short*)(wsb + off); off += 1179648;     // [768][768]
    unsigned short* h1b   = (unsigned short*)(wsb + off); off += ND * 2;      // alias: attnb
    unsigned short* vtg   = (unsigned short*)(wsb + off); off += (size_t)1024 * 14336;
    unsigned short* qkvb  = (unsigned short*)(wsb + off); off += (size_t)NTOK * QKVW * 2;
    unsigned short* attnb   = h1b;
    unsigned short* hiddenb = (unsigned short*)(wsb + pool0);  // [8192][3072] bf16 overlay

    // --- weight prep: single merged kernel (6 transposes + bias concat) ---
    prep_all_kernel<<<6921, dim3(32, 8), 0, stream>>>(
        Wq, Wk, Wv, Wo, W1, W2, bq, bk, bv, Wqkvt, Wot, W1t, W2t, bqkv);

    // 1. SLN1 -> h1b (bf16), copy x -> out[0:ND]
    sln_kernel<<<NTOK, 192, 0, stream>>>(h, x, g1, be1, ln1w, ln1b, h1b, out);

    // 2. fused QKV GEMM: [8192,768] @ [768,2304] -> qkvb bf16 (K part scaled -2)
    gemm_mfma_kernel<1, 0><<<dim3(NTOK/128, QKVW/128), 256, 0, stream>>>(
        h1b, Wqkvt, bqkv, nullptr, qkvb, NTOK, QKVW, D_);

    // 3. norms + V transpose tiles
    norms_kernel<<<NTOK, 256, 0, stream>>>(qkvb, q2g, k2g);
    vtrans_kernel<<<1024, 256, 0, stream>>>(qkvb, vtg);

    // 4. MFMA attention -> attnb bf16
    attn_mfma_kernel<<<1024, 256, 0, stream>>>(qkvb, vtg, q2g, k2g, attnb);

    // 5. Wo projection + residual h -> htmp fp32 (128x64 tiles: 768 blocks)
    gemm_mfma_n64_kernel<0, 0><<<dim3(NTOK/128, D_/64), 256, 0, stream>>>(
        attnb, Wot, bo, h, htmp, NTOK, D_, D_);

    // 6. SLN2 -> h2b bf16
    sln_kernel<<<NTOK, 192, 0, stream>>>(htmp, x, g2, be2, ln2w, ln2b, h2b, nullptr);

    // 7. MLP, full-size single dispatches
    gemm_mfma_kernel<1, 1><<<dim3(NTOK/128, DFF_/128), 256, 0, stream>>>(
        h2b, W1t, b1, nullptr, hiddenb, NTOK, DFF_, D_);
    gemm_mfma_n64_kernel<0, 0><<<dim3(NTOK/128, D_/64), 256, 0, stream>>>(
        hiddenb, W2t, b2, htmp, out + ND, NTOK, D_, DFF_);

    (void)in_sizes; (void)n_in; (void)out_size; (void)ws_size;
}

// Round 3
// 425.136 us; speedup vs baseline: 1.0098x; 1.0098x over previous
//
#include <hip/hip_runtime.h>
#include <math.h>

#define B_ 8
#define S_ 1024
#define D_ 768
#define H_ 8
#define DH_ 96
#define DFF_ 3072
#define NTOK (B_*S_)
#define QKVW 2304            // fused q|k|v width
#define EPS_ 1e-5f

typedef __attribute__((ext_vector_type(4))) float f4;
typedef __attribute__((ext_vector_type(4))) int i4;
typedef __attribute__((ext_vector_type(8))) __bf16 bf16x8;
typedef __attribute__((ext_vector_type(4))) unsigned short us4;
typedef __attribute__((ext_vector_type(8))) unsigned short us8;

static __device__ __forceinline__ unsigned short f2bf(float f) {
    unsigned int u = __builtin_bit_cast(unsigned int, f);
    u += 0x7fffu + ((u >> 16) & 1u);
    return (unsigned short)(u >> 16);
}
static __device__ __forceinline__ float bf2f(unsigned short u) {
    unsigned int x = ((unsigned int)u) << 16;
    return __builtin_bit_cast(float, x);
}

#define GLOBAL_LOAD_LDS16(g, l) \
    __builtin_amdgcn_global_load_lds((const __attribute__((address_space(1))) unsigned int*)(g), \
                                     (__attribute__((address_space(3))) unsigned int*)(l), 16, 0, 0)

// ---------------------------------------------------------------------------
// SLN: out_bf16 = bf16( x * (gamma * LayerNorm(h) + beta) ); optional x copy (fp32)
// ---------------------------------------------------------------------------
__global__ __launch_bounds__(192) void sln_kernel(
    const float* __restrict__ h, const float* __restrict__ x,
    const float* __restrict__ gamma, const float* __restrict__ beta,
    const float* __restrict__ w, const float* __restrict__ bvec,
    unsigned short* __restrict__ out_bf, float* __restrict__ xcopy)
{
    int row = blockIdx.x;
    int t = threadIdx.x;
    const float4* h4 = (const float4*)(h + (size_t)row * D_);
    const float4* x4 = (const float4*)(x + (size_t)row * D_);
    float4 hv = h4[t];
    float s  = hv.x + hv.y + hv.z + hv.w;
    float ss = hv.x*hv.x + hv.y*hv.y + hv.z*hv.z + hv.w*hv.w;
    #pragma unroll
    for (int off = 32; off > 0; off >>= 1) {
        s  += __shfl_down(s, off);
        ss += __shfl_down(ss, off);
    }
    __shared__ float red[2][3];
    int wid = t >> 6;
    if ((t & 63) == 0) { red[0][wid] = s; red[1][wid] = ss; }
    __syncthreads();
    float sum   = red[0][0] + red[0][1] + red[0][2];
    float sumsq = red[1][0] + red[1][1] + red[1][2];
    float mu  = sum * (1.0f / D_);
    float var = sumsq * (1.0f / D_) - mu * mu;
    float rstd = rsqrtf(var + EPS_);
    float g = gamma[0], be = beta[0];
    float4 wv = ((const float4*)w)[t];
    float4 bv = ((const float4*)bvec)[t];
    float4 xv = x4[t];
    us4 o;
    o.x = f2bf(xv.x * (g * ((hv.x - mu) * rstd * wv.x + bv.x) + be));
    o.y = f2bf(xv.y * (g * ((hv.y - mu) * rstd * wv.y + bv.y) + be));
    o.z = f2bf(xv.z * (g * ((hv.z - mu) * rstd * wv.z + bv.z) + be));
    o.w = f2bf(xv.w * (g * ((hv.w - mu) * rstd * wv.w + bv.w) + be));
    *(us4*)(out_bf + (size_t)row * D_ + t * 4) = o;
    if (xcopy) ((float4*)(xcopy + (size_t)row * D_))[t] = xv;
}

// ---------------------------------------------------------------------------
// Merged weight prep: all 6 transposes (fp32->bf16, [K][N]->[N][K]) + bias concat
// Wk and bk are pre-scaled by -2 so the attention QK^T MFMA emits -2*q.k
// directly (L2-distance expansion); norms_kernel compensates k2 by *0.25.
// ---------------------------------------------------------------------------
__global__ __launch_bounds__(256) void prep_all_kernel(
    const float* __restrict__ Wq, const float* __restrict__ Wk,
    const float* __restrict__ Wv, const float* __restrict__ Wo,
    const float* __restrict__ W1, const float* __restrict__ W2,
    const float* __restrict__ bq, const float* __restrict__ bk, const float* __restrict__ bv,
    unsigned short* __restrict__ Wqkvt, unsigned short* __restrict__ Wot,
    unsigned short* __restrict__ W1t, unsigned short* __restrict__ W2t,
    float* __restrict__ bqkv)
{
    int id = blockIdx.x;
    int tx = threadIdx.x, ty = threadIdx.y;
    if (id >= 6912) {   // bias concat: 9 blocks x 256 threads
        int i = (id - 6912) * 256 + ty * 32 + tx;
        if (i < QKVW) {
            float v = (i < 768) ? bq[i] : (i < 1536) ? -2.f * bk[i - 768] : bv[i - 1536];
            bqkv[i] = v;
        }
        return;
    }
    const float* in; unsigned short* out; int K, N, nbx, rel;
    float scl = 1.f;
    if (id < 1728)      { int m = id / 576; rel = id % 576;
                          in = (m == 0) ? Wq : (m == 1) ? Wk : Wv;
                          if (m == 1) scl = -2.f;
                          out = Wqkvt + (size_t)m * 768 * 768; K = 768; N = 768; nbx = 24; }
    else if (id < 2304) { rel = id - 1728; in = Wo; out = Wot;  K = 768;  N = 768;  nbx = 24; }
    else if (id < 4608) { rel = id - 2304; in = W1; out = W1t;  K = 768;  N = 3072; nbx = 96; }
    else                { rel = id - 4608; in = W2; out = W2t;  K = 3072; N = 768;  nbx = 24; }
    int n0 = (rel % nbx) * 32, k0 = (rel / nbx) * 32;
    __shared__ float tile[32][33];
    #pragma unroll
    for (int r = 0; r < 4; r++)
        tile[ty + r * 8][tx] = in[(size_t)(k0 + ty + r * 8) * N + n0 + tx];
    __syncthreads();
    #pragma unroll
    for (int r = 0; r < 4; r++)
        out[(size_t)(n0 + ty + r * 8) * K + k0 + tx] = f2bf(scl * tile[tx][ty + r * 8]);
}

// ---------------------------------------------------------------------------
// bf16 MFMA GEMM, 128x128 tile, BK=32, double-buffered prefetch (T3 2-phase),
// XOR chunk-swizzled LDS (pre-swizzled global source, linear gload_lds dest).
// ---------------------------------------------------------------------------
template<int OUT_BF16, int RELU>
__global__ __launch_bounds__(256) void gemm_mfma_kernel(
    const unsigned short* __restrict__ A, const unsigned short* __restrict__ Bt,
    const float* __restrict__ bias, const float* __restrict__ resid,
    void* __restrict__ Cout, int M, int N, int K)
{
    __shared__ unsigned short Asm[2][128 * 32];
    __shared__ unsigned short Bsm[2][128 * 32];

    int t = threadIdx.x;
    int lane = t & 63, wv = t >> 6;
    int wm = wv & 1, wn = wv >> 1;
    int l16 = lane & 15, quad = lane >> 4;

    int bm = blockIdx.x * 128;
    int bn = blockIdx.y * 128;

    const unsigned short* Abase = A  + (size_t)bm * K;
    const unsigned short* Bbase = Bt + (size_t)bn * K;

    // staging: fl in [0,1024): row = fl>>2 (4x16B chunks/row of 32 shorts),
    // phys chunk p = fl&3 holds logical chunk l = (fl ^ (fl>>3)) & 3.
    int fl0 = t, fl1 = 256 + t;
    int r0 = fl0 >> 2, lg0 = (fl0 ^ (fl0 >> 3)) & 3;
    int r1 = fl1 >> 2, lg1 = (fl1 ^ (fl1 >> 3)) & 3;

    f4 acc[4][4] = {};   // acc[j][i]: j = weight (col) tile, i = act (row) tile

    // prologue stage
    GLOBAL_LOAD_LDS16(Abase + (size_t)r0 * K + lg0 * 8, &Asm[0][fl0 * 8]);
    GLOBAL_LOAD_LDS16(Abase + (size_t)r1 * K + lg1 * 8, &Asm[0][fl1 * 8]);
    GLOBAL_LOAD_LDS16(Bbase + (size_t)r0 * K + lg0 * 8, &Bsm[0][fl0 * 8]);
    GLOBAL_LOAD_LDS16(Bbase + (size_t)r1 * K + lg1 * 8, &Bsm[0][fl1 * 8]);
    __syncthreads();

    int nk = K >> 5;
    int cur = 0;
    for (int it = 0; it < nk; ++it) {
        if (it + 1 < nk) {
            int k0 = (it + 1) << 5;
            GLOBAL_LOAD_LDS16(Abase + (size_t)r0 * K + k0 + lg0 * 8, &Asm[cur ^ 1][fl0 * 8]);
            GLOBAL_LOAD_LDS16(Abase + (size_t)r1 * K + k0 + lg1 * 8, &Asm[cur ^ 1][fl1 * 8]);
            GLOBAL_LOAD_LDS16(Bbase + (size_t)r0 * K + k0 + lg0 * 8, &Bsm[cur ^ 1][fl0 * 8]);
            GLOBAL_LOAD_LDS16(Bbase + (size_t)r1 * K + k0 + lg1 * 8, &Bsm[cur ^ 1][fl1 * 8]);
        }

        bf16x8 xf[4], wf[4];
        #pragma unroll
        for (int i = 0; i < 4; i++) {
            int m = wm * 64 + i * 16 + l16;
            int p = (quad ^ (m >> 1)) & 3;
            xf[i] = __builtin_bit_cast(bf16x8, *(const i4*)&Asm[cur][m * 32 + p * 8]);
        }
        #pragma unroll
        for (int j = 0; j < 4; j++) {
            int n = wn * 64 + j * 16 + l16;
            int p = (quad ^ (n >> 1)) & 3;
            wf[j] = __builtin_bit_cast(bf16x8, *(const i4*)&Bsm[cur][n * 32 + p * 8]);
        }
        #pragma unroll
        for (int j = 0; j < 4; j++)
            #pragma unroll
            for (int i = 0; i < 4; i++)
                acc[j][i] = __builtin_amdgcn_mfma_f32_16x16x32_bf16(wf[j], xf[i], acc[j][i], 0, 0, 0);

        __syncthreads();   // drains prefetch (vmcnt) + protects cur buffer reuse
        cur ^= 1;
    }

    #pragma unroll
    for (int i = 0; i < 4; i++) {
        int rowg = bm + wm * 64 + i * 16 + l16;
        #pragma unroll
        for (int j = 0; j < 4; j++) {
            int colg0 = bn + wn * 64 + j * 16 + quad * 4;
            f4 v = acc[j][i];
            f4 b4 = *(const f4*)&bias[colg0];
            v += b4;
            if (RELU) {
                #pragma unroll
                for (int r = 0; r < 4; r++) v[r] = fmaxf(v[r], 0.f);
            }
            if (resid) {
                f4 r4 = *(const f4*)&resid[(size_t)rowg * N + colg0];
                v += r4;
            }
            if (OUT_BF16) {
                us4 o;
                o.x = f2bf(v[0]); o.y = f2bf(v[1]); o.z = f2bf(v[2]); o.w = f2bf(v[3]);
                *(us4*)((unsigned short*)Cout + (size_t)rowg * N + colg0) = o;
            } else {
                *(f4*)((float*)Cout + (size_t)rowg * N + colg0) = v;
            }
        }
    }
}

// ---------------------------------------------------------------------------
// bf16 MFMA GEMM, 128x64 tile, BK=64, double-buffered prefetch + XOR swizzle.
// LDS 48KB -> 3 blocks/CU (matches 768-block grid for N=768 GEMMs).
// ---------------------------------------------------------------------------
template<int OUT_BF16, int RELU>
__global__ __launch_bounds__(256) void gemm_mfma_n64_kernel(
    const unsigned short* __restrict__ A, const unsigned short* __restrict__ Bt,
    const float* __restrict__ bias, const float* __restrict__ resid,
    void* __restrict__ Cout, int M, int N, int K)
{
    __shared__ unsigned short Asm[2][128 * 64];
    __shared__ unsigned short Bsm[2][64 * 64];

    int t = threadIdx.x;
    int lane = t & 63, wv = t >> 6;
    int wm = wv & 1, wn = wv >> 1;
    int l16 = lane & 15, quad = lane >> 4;

    int bm = blockIdx.x * 128;
    int bn = blockIdx.y * 64;

    const unsigned short* Abase = A  + (size_t)bm * K;
    const unsigned short* Bbase = Bt + (size_t)bn * K;

    // staging: row = fl>>3 (8x16B chunks/row of 64 shorts),
    // phys chunk p = fl&7 holds logical chunk l = (fl ^ (fl>>3)) & 7.
    int ar[4], alg[4], br[2], blg[2];
    #pragma unroll
    for (int i = 0; i < 4; i++) {
        int fl = t + i * 256;
        ar[i] = fl >> 3; alg[i] = (fl ^ (fl >> 3)) & 7;
    }
    #pragma unroll
    for (int i = 0; i < 2; i++) {
        int fl = t + i * 256;
        br[i] = fl >> 3; blg[i] = (fl ^ (fl >> 3)) & 7;
    }

    f4 acc[2][4] = {};

    // prologue stage (buffer 0, k=0)
    #pragma unroll
    for (int i = 0; i < 4; i++)
        GLOBAL_LOAD_LDS16(Abase + (size_t)ar[i] * K + alg[i] * 8, &Asm[0][(t + i * 256) * 8]);
    #pragma unroll
    for (int i = 0; i < 2; i++)
        GLOBAL_LOAD_LDS16(Bbase + (size_t)br[i] * K + blg[i] * 8, &Bsm[0][(t + i * 256) * 8]);
    __syncthreads();

    int nk = K >> 6;
    int cur = 0;
    for (int it = 0; it < nk; ++it) {
        if (it + 1 < nk) {
            int k0 = (it + 1) << 6;
            #pragma unroll
            for (int i = 0; i < 4; i++)
                GLOBAL_LOAD_LDS16(Abase + (size_t)ar[i] * K + k0 + alg[i] * 8, &Asm[cur ^ 1][(t + i * 256) * 8]);
            #pragma unroll
            for (int i = 0; i < 2; i++)
                GLOBAL_LOAD_LDS16(Bbase + (size_t)br[i] * K + k0 + blg[i] * 8, &Bsm[cur ^ 1][(t + i * 256) * 8]);
        }

        #pragma unroll
        for (int kk = 0; kk < 2; kk++) {
            bf16x8 xf[4], wf[2];
            #pragma unroll
            for (int i = 0; i < 4; i++) {
                int m = wm * 64 + i * 16 + l16;
                int p = ((kk * 4 + quad) ^ (m & 7)) & 7;
                xf[i] = __builtin_bit_cast(bf16x8, *(const i4*)&Asm[cur][m * 64 + p * 8]);
            }
            #pragma unroll
            for (int j = 0; j < 2; j++) {
                int n = wn * 32 + j * 16 + l16;
                int p = ((kk * 4 + quad) ^ (n & 7)) & 7;
                wf[j] = __builtin_bit_cast(bf16x8, *(const i4*)&Bsm[cur][n * 64 + p * 8]);
            }
            #pragma unroll
            for (int j = 0; j < 2; j++)
                #pragma unroll
                for (int i = 0; i < 4; i++)
                    acc[j][i] = __builtin_amdgcn_mfma_f32_16x16x32_bf16(wf[j], xf[i], acc[j][i], 0, 0, 0);
        }

        __syncthreads();   // drains prefetch + protects cur buffer reuse
        cur ^= 1;
    }

    #pragma unroll
    for (int i = 0; i < 4; i++) {
        int rowg = bm + wm * 64 + i * 16 + l16;
        #pragma unroll
        for (int j = 0; j < 2; j++) {
            int colg0 = bn + wn * 32 + j * 16 + quad * 4;
            f4 v = acc[j][i];
            f4 b4 = *(const f4*)&bias[colg0];
            v += b4;
            if (RELU) {
                #pragma unroll
                for (int r = 0; r < 4; r++) v[r] = fmaxf(v[r], 0.f);
            }
            if (resid) {
                f4 r4 = *(const f4*)&resid[(size_t)rowg * N + colg0];
                v += r4;
            }
            if (OUT_BF16) {
                us4 o;
                o.x = f2bf(v[0]); o.y = f2bf(v[1]); o.z = f2bf(v[2]); o.w = f2bf(v[3]);
                *(us4*)((unsigned short*)Cout + (size_t)rowg * N + colg0) = o;
            } else {
                *(f4*)((float*)Cout + (size_t)rowg * N + colg0) = v;
            }
        }
    }
}

// ---------------------------------------------------------------------------
// q2/k2 norms from fused qkv bf16 buffer [NTOK][2304] -> q2g,k2g [B*H*S] fp32
// K in qkvb is pre-scaled by -2 (see prep_all_kernel) -> k2 = 0.25 * sum(K'^2)
// ---------------------------------------------------------------------------
__global__ __launch_bounds__(256) void norms_kernel(
    const unsigned short* __restrict__ qkv, float* __restrict__ q2g, float* __restrict__ k2g)
{
    int row = blockIdx.x;
    int t = threadIdx.x;
    int hh = t >> 5, l32 = t & 31;
    const unsigned short* base = qkv + (size_t)row * QKVW + hh * DH_ + l32 * 3;
    float qs = 0.f, ks = 0.f;
    #pragma unroll
    for (int e = 0; e < 3; e++) {
        float qv = bf2f(base[e]);
        float kv = bf2f(base[768 + e]);
        qs += qv * qv; ks += kv * kv;
    }
    #pragma unroll
    for (int off = 16; off > 0; off >>= 1) {
        qs += __shfl_xor(qs, off, 32);
        ks += __shfl_xor(ks, off, 32);
    }
    if (l32 == 0) {
        int b = row >> 10, s = row & 1023;
        int idx = (b * H_ + hh) * S_ + s;
        q2g[idx] = qs; k2g[idx] = ks * 0.25f;
    }
}

// ---------------------------------------------------------------------------
// V transpose into padded tiles: qkv V-part -> vt[(bh*16+kt)] tile of [96][72] bf16
// ---------------------------------------------------------------------------
__global__ __launch_bounds__(256) void vtrans_kernel(
    const unsigned short* __restrict__ qkv, unsigned short* __restrict__ vt)
{
    __shared__ unsigned short Vl[64][100];
    int blk = blockIdx.x;          // bh*16 + kt
    int bh = blk >> 4, kt = blk & 15;
    int b = bh >> 3, hh = bh & 7;
    int t = threadIdx.x;
    int key = t >> 2, qc = t & 3;
    const unsigned short* src = qkv + ((size_t)(b * S_ + kt * 64 + key)) * QKVW + 1536 + hh * DH_;
    #pragma unroll
    for (int i = 0; i < 3; i++) {
        int chunk = qc + i * 4;            // 0..11, 8 shorts each
        us8 v = *(const us8*)(src + chunk * 8);
        #pragma unroll
        for (int e = 0; e < 8; e++) Vl[key][chunk * 8 + e] = v[e];
    }
    __syncthreads();
    unsigned short* dst = vt + (size_t)blk * 7168;
    #pragma unroll
    for (int r = 0; r < 3; r++) {
        int c = r * 256 + t;               // 0..767
        int vd = c >> 3, kc = c & 7;
        us8 o;
        #pragma unroll
        for (int j = 0; j < 8; j++) o[j] = Vl[kc * 8 + j][vd];
        *(us8*)(dst + vd * 72 + kc * 8) = o;
    }
}

// ---------------------------------------------------------------------------
// MFMA flash attention with L2 distances. K pre-scaled by -2, q2+k2 in the
// MFMA C-initializer -> d2 directly. 2 q-frags/wave (32 q-rows, 2x ILP on the
// sqrt/exp2 chain; kf/vf LDS reads amortized over both frags). K/V staging
// double-buffered: next key-tile's global_load_lds issued before this tile's
// compute, single barrier/iter. grid = 512 blocks (64 bh x 4 qtiles... 8
// qtiles of 128 rows), 2 blocks/CU. XCD swizzle: one batch per XCD.
// ---------------------------------------------------------------------------
__global__ __launch_bounds__(256, 2) void attn_mfma_kernel(
    const unsigned short* __restrict__ qkv,
    const unsigned short* __restrict__ vt,
    const float* __restrict__ q2g, const float* __restrict__ k2g,
    unsigned short* __restrict__ outb)
{
    __shared__ unsigned short Klds[2][6144];     // chunk-major: [dc 0..11][key 0..63][8]
    __shared__ unsigned short Vlds[2][7168];     // [vdim][72]
    __shared__ unsigned short Plds[4][2][16 * 72];  // per-wave per-frag [qrow][key]

    int t = threadIdx.x;
    int lane = t & 63, w = t >> 6;
    int l16 = lane & 15, quad = lane >> 4;

    // XCD swizzle: bid%8 selects XCD; each XCD gets one batch
    // (8 heads x 8 qtiles = 64 blocks).
    int bid = blockIdx.x;
    int slot = bid >> 3;
    int bh = (bid & 7) * 8 + (slot >> 3);
    int qt = slot & 7;
    int b = bh >> 3, hh = bh & 7;

    int qrowW = qt * 128 + w * 32;    // this wave's first q-row (32 rows, 2 frags)

    const unsigned short* qb = qkv + ((size_t)(b * S_ + qrowW)) * QKVW + hh * DH_;
    bf16x8 qf[2][3];
    #pragma unroll
    for (int f = 0; f < 2; f++)
        #pragma unroll
        for (int d = 0; d < 3; d++)
            qf[f][d] = __builtin_bit_cast(bf16x8,
                *(const i4*)(qb + (size_t)(f * 16 + l16) * QKVW + d * 32 + quad * 8));

    float q2n[2];
    #pragma unroll
    for (int f = 0; f < 2; f++)
        q2n[f] = q2g[bh * S_ + qrowW + f * 16 + l16];

    float lsum0 = 0.f, lsum1 = 0.f;
    f4 Oacc[2][6] = {};

    const float cexp = 0.14724445f;   // log2(e)/sqrt(96)

    const unsigned short* kgb = qkv + ((size_t)(b * S_)) * QKVW + 768 + hh * DH_;
    const unsigned short* vgb0 = vt + (size_t)(bh * 16) * 7168;
    const float* k2base = k2g + bh * S_;

    // K staging indices: c in [0,768): key = c&63, dc = c>>6 (chunk-major dest)
    int kkey = t & 63;  // for r-loop: c = r*256+t -> key=(r*256+t)&63 = t&63 (256%64==0)
    // stage one key-tile into buffer bb
    #define ATTN_STAGE(bb, itv)                                                   \
        {                                                                         \
            _Pragma("unroll")                                                     \
            for (int r = 0; r < 3; r++) {                                         \
                int c = r * 256 + t;                                              \
                int dc = c >> 6;                                                  \
                GLOBAL_LOAD_LDS16(kgb + ((size_t)((itv) * 64 + kkey)) * QKVW + dc * 8, \
                                  &Klds[bb][c * 8]);                              \
            }                                                                     \
            const unsigned short* vgb = vgb0 + (size_t)(itv) * 7168;              \
            _Pragma("unroll")                                                     \
            for (int r = 0; r < 3; r++)                                           \
                GLOBAL_LOAD_LDS16(vgb + (r * 256 + t) * 8, &Vlds[bb][(r * 256 + t) * 8]); \
            if (t < 128)                                                          \
                GLOBAL_LOAD_LDS16(vgb + (768 + t) * 8, &Vlds[bb][(768 + t) * 8]); \
        }

    ATTN_STAGE(0, 0);
    __syncthreads();

    for (int it = 0; it < 16; it++) {
        int cur = it & 1;
        if (it) __syncthreads();          // prev prefetch landed; prev reads done
        if (it + 1 < 16) ATTN_STAGE(cur ^ 1, it + 1);   // overlap with compute below

        float4 k2f[4];
        #pragma unroll
        for (int kt2 = 0; kt2 < 4; kt2++)
            k2f[kt2] = *(const float4*)(k2base + it * 64 + kt2 * 16 + quad * 4);

        // S^T = K' . Q^T + (q2+k2) : C-frag col(l16)=qrow, row(quad*4+r)=key
        const unsigned short* kB = &Klds[cur][quad * 512 + l16 * 8];
        #pragma unroll
        for (int kt2 = 0; kt2 < 4; kt2++) {
            const unsigned short* kp = kB + kt2 * 128;
            bf16x8 kf0 = __builtin_bit_cast(bf16x8, *(const i4*)(kp));
            bf16x8 kf1 = __builtin_bit_cast(bf16x8, *(const i4*)(kp + 2048));
            bf16x8 kf2 = __builtin_bit_cast(bf16x8, *(const i4*)(kp + 4096));
            #pragma unroll
            for (int f = 0; f < 2; f++) {
                f4 a = {k2f[kt2].x + q2n[f], k2f[kt2].y + q2n[f],
                        k2f[kt2].z + q2n[f], k2f[kt2].w + q2n[f]};
                a = __builtin_amdgcn_mfma_f32_16x16x32_bf16(kf0, qf[f][0], a, 0, 0, 0);
                a = __builtin_amdgcn_mfma_f32_16x16x32_bf16(kf1, qf[f][1], a, 0, 0, 0);
                a = __builtin_amdgcn_mfma_f32_16x16x32_bf16(kf2, qf[f][2], a, 0, 0, 0);
                #pragma unroll
                for (int r2 = 0; r2 < 4; r2++) {
                    float d2 = fmaxf(a[r2], 0.f);
                    float p = exp2f(-__builtin_amdgcn_sqrtf(d2) * cexp);
                    if (f == 0) lsum0 += p; else lsum1 += p;
                    a[r2] = p;
                }
                unsigned int plo, phi;
                asm("v_cvt_pk_bf16_f32 %0, %1, %2" : "=v"(plo) : "v"(a[0]), "v"(a[1]));
                asm("v_cvt_pk_bf16_f32 %0, %1, %2" : "=v"(phi) : "v"(a[2]), "v"(a[3]));
                uint2 pkd; pkd.x = plo; pkd.y = phi;
                *(uint2*)&Plds[w][f][l16 * 72 + kt2 * 16 + quad * 4] = pkd;
            }
        }
        // O += P . V (no rescale needed: fixed shift)
        bf16x8 pa[2][2];
        #pragma unroll
        for (int f = 0; f < 2; f++) {
            pa[f][0] = __builtin_bit_cast(bf16x8, *(const i4*)&Plds[w][f][l16 * 72 + quad * 8]);
            pa[f][1] = __builtin_bit_cast(bf16x8, *(const i4*)&Plds[w][f][l16 * 72 + 32 + quad * 8]);
        }
        #pragma unroll
        for (int vtl = 0; vtl < 6; vtl++) {
            bf16x8 vf0 = __builtin_bit_cast(bf16x8, *(const i4*)&Vlds[cur][(vtl * 16 + l16) * 72 + quad * 8]);
            bf16x8 vf1 = __builtin_bit_cast(bf16x8, *(const i4*)&Vlds[cur][(vtl * 16 + l16) * 72 + 32 + quad * 8]);
            #pragma unroll
            for (int f = 0; f < 2; f++) {
                Oacc[f][vtl] = __builtin_amdgcn_mfma_f32_16x16x32_bf16(pa[f][0], vf0, Oacc[f][vtl], 0, 0, 0);
                Oacc[f][vtl] = __builtin_amdgcn_mfma_f32_16x16x32_bf16(pa[f][1], vf1, Oacc[f][vtl], 0, 0, 0);
            }
        }
    }
    // deferred l-reduction over the 4 quads, per frag
    #pragma unroll
    for (int f = 0; f < 2; f++) {
        float ls = (f == 0) ? lsum0 : lsum1;
        ls += __shfl_xor(ls, 16, 64);
        ls += __shfl_xor(ls, 32, 64);
        float inv_l = 1.f / ls;
        f4 iv;
        #pragma unroll
        for (int r2 = 0; r2 < 4; r2++)
            iv[r2] = __shfl(inv_l, quad * 4 + r2, 64);
        #pragma unroll
        for (int vtl = 0; vtl < 6; vtl++)
            #pragma unroll
            for (int r2 = 0; r2 < 4; r2++) {
                int row = b * S_ + qrowW + f * 16 + quad * 4 + r2;
                outb[(size_t)row * D_ + hh * DH_ + vtl * 16 + l16] = f2bf(Oacc[f][vtl][r2] * iv[r2]);
            }
    }
    #undef ATTN_STAGE
}

// ---------------------------------------------------------------------------
extern "C" void kernel_launch(void* const* d_in, const int* in_sizes, int n_in,
                              void* d_out, int out_size, void* d_ws, size_t ws_size,
                              hipStream_t stream)
{
    const float* h    = (const float*)d_in[0];
    const float* x    = (const float*)d_in[1];
    const float* g1   = (const float*)d_in[2];
    const float* be1  = (const float*)d_in[3];
    const float* ln1w = (const float*)d_in[4];
    const float* ln1b = (const float*)d_in[5];
    const float* g2   = (const float*)d_in[6];
    const float* be2  = (const float*)d_in[7];
    const float* ln2w = (const float*)d_in[8];
    const float* ln2b = (const float*)d_in[9];
    const float* Wq   = (const float*)d_in[10];
    const float* bq   = (const float*)d_in[11];
    const float* Wk   = (const float*)d_in[12];
    const float* bk   = (const float*)d_in[13];
    const float* Wv   = (const float*)d_in[14];
    const float* bv   = (const float*)d_in[15];
    const float* Wo   = (const float*)d_in[16];
    const float* bo   = (const float*)d_in[17];
    const float* W1   = (const float*)d_in[18];
    const float* b1   = (const float*)d_in[19];
    const float* W2   = (const float*)d_in[20];
    const float* b2   = (const float*)d_in[21];

    float* out = (float*)d_out;
    char* wsb = (char*)d_ws;
    const size_t ND = (size_t)NTOK * D_;

    // workspace layout (bytes): persistent region first, dead-pool last so
    // the full-size MLP hidden (50.3 MB bf16) can overlay the dead pool.
    size_t off = 0;
    unsigned short* W1t = (unsigned short*)(wsb + off); off += 4718592;       // [3072][768]
    unsigned short* W2t = (unsigned short*)(wsb + off); off += 4718592;       // [768][3072]
    float* bqkv = (float*)(wsb + off);                  off += 16384;
    float* htmp = (float*)(wsb + off);                  off += ND * 4;        // fp32
    float* q2g  = (float*)(wsb + off);                  off += (size_t)B_ * H_ * S_ * 4;
    float* k2g  = (float*)(wsb + off);                  off += (size_t)B_ * H_ * S_ * 4;
    unsigned short* h2b = (unsigned short*)(wsb + off); off += ND * 2;        // SLN2 out
    // ---- dead pool (all dead before the MLP) ----
    size_t pool0 = off;
    unsigned short* Wqkvt = (unsigned short*)(wsb + off); off += 3538944;     // [2304][768]
    unsigned short* Wot   = (unsigned short*)(wsb + off); off += 1179648;     // [768][768]
    unsigned short* h1b   = (unsigned short*)(wsb + off); off += ND * 2;      // alias: attnb
    unsigned short* vtg   = (unsigned short*)(wsb + off); off += (size_t)1024 * 14336;
    unsigned short* qkvb  = (unsigned short*)(wsb + off); off += (size_t)NTOK * QKVW * 2;
    unsigned short* attnb   = h1b;
    unsigned short* hiddenb = (unsigned short*)(wsb + pool0);  // [8192][3072] bf16 overlay

    // --- weight prep: single merged kernel (6 transposes + bias concat) ---
    prep_all_kernel<<<6921, dim3(32, 8), 0, stream>>>(
        Wq, Wk, Wv, Wo, W1, W2, bq, bk, bv, Wqkvt, Wot, W1t, W2t, bqkv);

    // 1. SLN1 -> h1b (bf16), copy x -> out[0:ND]
    sln_kernel<<<NTOK, 192, 0, stream>>>(h, x, g1, be1, ln1w, ln1b, h1b, out);

    // 2. fused QKV GEMM: [8192,768] @ [768,2304] -> qkvb bf16 (K part scaled -2)
    gemm_mfma_kernel<1, 0><<<dim3(NTOK/128, QKVW/128), 256, 0, stream>>>(
        h1b, Wqkvt, bqkv, nullptr, qkvb, NTOK, QKVW, D_);

    // 3. norms + V transpose tiles
    norms_kernel<<<NTOK, 256, 0, stream>>>(qkvb, q2g, k2g);
    vtrans_kernel<<<1024, 256, 0, stream>>>(qkvb, vtg);

    // 4. MFMA attention -> attnb bf16 (512 blocks: 64 bh x 8 q-tiles of 128)
    attn_mfma_kernel<<<512, 256, 0, stream>>>(qkvb, vtg, q2g, k2g, attnb);

    // 5. Wo projection + residual h -> htmp fp32 (128x64 tiles: 768 blocks)
    gemm_mfma_n64_kernel<0, 0><<<dim3(NTOK/128, D_/64), 256, 0, stream>>>(
        attnb, Wot, bo, h, htmp, NTOK, D_, D_);

    // 6. SLN2 -> h2b bf16
    sln_kernel<<<NTOK, 192, 0, stream>>>(htmp, x, g2, be2, ln2w, ln2b, h2b, nullptr);

    // 7. MLP, full-size single dispatches
    gemm_mfma_kernel<1, 1><<<dim3(NTOK/128, DFF_/128), 256, 0, stream>>>(
        h2b, W1t, b1, nullptr, hiddenb, NTOK, DFF_, D_);
    gemm_mfma_n64_kernel<0, 0><<<dim3(NTOK/128, D_/64), 256, 0, stream>>>(
        hiddenb, W2t, b2, htmp, out + ND, NTOK, D_, DFF_);

    (void)in_sizes; (void)n_in; (void)out_size; (void)ws_size;
}

// Round 5
// 405.570 us; speedup vs baseline: 1.0586x; 1.0482x over previous
//
#include <hip/hip_runtime.h>
#include <math.h>

#define B_ 8
#define S_ 1024
#define D_ 768
#define H_ 8
#define DH_ 96
#define DFF_ 3072
#define NTOK (B_*S_)
#define QKVW 2304            // fused q|k|v width
#define EPS_ 1e-5f
#define CEXP_ 0.14724445f    // log2(e)/sqrt(96), folded into Wq/Wk scaling

typedef __attribute__((ext_vector_type(4))) float f4;
typedef __attribute__((ext_vector_type(4))) int i4;
typedef __attribute__((ext_vector_type(8))) __bf16 bf16x8;
typedef __attribute__((ext_vector_type(4))) unsigned short us4;
typedef __attribute__((ext_vector_type(8))) unsigned short us8;

static __device__ __forceinline__ unsigned short f2bf(float f) {
    unsigned int u = __builtin_bit_cast(unsigned int, f);
    u += 0x7fffu + ((u >> 16) & 1u);
    return (unsigned short)(u >> 16);
}
static __device__ __forceinline__ float bf2f(unsigned short u) {
    unsigned int x = ((unsigned int)u) << 16;
    return __builtin_bit_cast(float, x);
}

#define GLOBAL_LOAD_LDS16(g, l) \
    __builtin_amdgcn_global_load_lds((const __attribute__((address_space(1))) unsigned int*)(g), \
                                     (__attribute__((address_space(3))) unsigned int*)(l), 16, 0, 0)

// ---------------------------------------------------------------------------
// SLN: out_bf16 = bf16( x * (gamma * LayerNorm(h) + beta) ); optional x copy (fp32)
// ---------------------------------------------------------------------------
__global__ __launch_bounds__(192) void sln_kernel(
    const float* __restrict__ h, const float* __restrict__ x,
    const float* __restrict__ gamma, const float* __restrict__ beta,
    const float* __restrict__ w, const float* __restrict__ bvec,
    unsigned short* __restrict__ out_bf, float* __restrict__ xcopy)
{
    int row = blockIdx.x;
    int t = threadIdx.x;
    const float4* h4 = (const float4*)(h + (size_t)row * D_);
    const float4* x4 = (const float4*)(x + (size_t)row * D_);
    float4 hv = h4[t];
    float s  = hv.x + hv.y + hv.z + hv.w;
    float ss = hv.x*hv.x + hv.y*hv.y + hv.z*hv.z + hv.w*hv.w;
    #pragma unroll
    for (int off = 32; off > 0; off >>= 1) {
        s  += __shfl_down(s, off);
        ss += __shfl_down(ss, off);
    }
    __shared__ float red[2][3];
    int wid = t >> 6;
    if ((t & 63) == 0) { red[0][wid] = s; red[1][wid] = ss; }
    __syncthreads();
    float sum   = red[0][0] + red[0][1] + red[0][2];
    float sumsq = red[1][0] + red[1][1] + red[1][2];
    float mu  = sum * (1.0f / D_);
    float var = sumsq * (1.0f / D_) - mu * mu;
    float rstd = rsqrtf(var + EPS_);
    float g = gamma[0], be = beta[0];
    float4 wv = ((const float4*)w)[t];
    float4 bv = ((const float4*)bvec)[t];
    float4 xv = x4[t];
    us4 o;
    o.x = f2bf(xv.x * (g * ((hv.x - mu) * rstd * wv.x + bv.x) + be));
    o.y = f2bf(xv.y * (g * ((hv.y - mu) * rstd * wv.y + bv.y) + be));
    o.z = f2bf(xv.z * (g * ((hv.z - mu) * rstd * wv.z + bv.z) + be));
    o.w = f2bf(xv.w * (g * ((hv.w - mu) * rstd * wv.w + bv.w) + be));
    *(us4*)(out_bf + (size_t)row * D_ + t * 4) = o;
    if (xcopy) ((float4*)(xcopy + (size_t)row * D_))[t] = xv;
}

// ---------------------------------------------------------------------------
// Merged weight prep: all 6 transposes (fp32->bf16, [K][N]->[N][K]) + bias concat
// Wq/bq scaled by cexp, Wk/bk by -2*cexp: the attention QK^T MFMA then emits
// cexp^2 * (-2 q.k); q2/k2 computed from the scaled values carry cexp^2 too,
// so d2' = cexp^2 * d2 and p = exp2(-sqrt(d2')) with no per-score multiply.
// ---------------------------------------------------------------------------
__global__ __launch_bounds__(256) void prep_all_kernel(
    const float* __restrict__ Wq, const float* __restrict__ Wk,
    const float* __restrict__ Wv, const float* __restrict__ Wo,
    const float* __restrict__ W1, const float* __restrict__ W2,
    const float* __restrict__ bq, const float* __restrict__ bk, const float* __restrict__ bv,
    unsigned short* __restrict__ Wqkvt, unsigned short* __restrict__ Wot,
    unsigned short* __restrict__ W1t, unsigned short* __restrict__ W2t,
    float* __restrict__ bqkv)
{
    int id = blockIdx.x;
    int tx = threadIdx.x, ty = threadIdx.y;
    if (id >= 6912) {   // bias concat: 9 blocks x 256 threads
        int i = (id - 6912) * 256 + ty * 32 + tx;
        if (i < QKVW) {
            float v = (i < 768) ? CEXP_ * bq[i]
                    : (i < 1536) ? -2.f * CEXP_ * bk[i - 768] : bv[i - 1536];
            bqkv[i] = v;
        }
        return;
    }
    const float* in; unsigned short* out; int K, N, nbx, rel;
    float scl = 1.f;
    if (id < 1728)      { int m = id / 576; rel = id % 576;
                          in = (m == 0) ? Wq : (m == 1) ? Wk : Wv;
                          if (m == 0) scl = CEXP_;
                          if (m == 1) scl = -2.f * CEXP_;
                          out = Wqkvt + (size_t)m * 768 * 768; K = 768; N = 768; nbx = 24; }
    else if (id < 2304) { rel = id - 1728; in = Wo; out = Wot;  K = 768;  N = 768;  nbx = 24; }
    else if (id < 4608) { rel = id - 2304; in = W1; out = W1t;  K = 768;  N = 3072; nbx = 96; }
    else                { rel = id - 4608; in = W2; out = W2t;  K = 3072; N = 768;  nbx = 24; }
    int n0 = (rel % nbx) * 32, k0 = (rel / nbx) * 32;
    __shared__ float tile[32][33];
    #pragma unroll
    for (int r = 0; r < 4; r++)
        tile[ty + r * 8][tx] = in[(size_t)(k0 + ty + r * 8) * N + n0 + tx];
    __syncthreads();
    #pragma unroll
    for (int r = 0; r < 4; r++)
        out[(size_t)(n0 + ty + r * 8) * K + k0 + tx] = f2bf(scl * tile[tx][ty + r * 8]);
}

// ---------------------------------------------------------------------------
// bf16 MFMA GEMM, 128x128 tile, BK=32, double-buffered prefetch (T3 2-phase),
// XOR chunk-swizzled LDS (pre-swizzled global source, linear gload_lds dest).
// ---------------------------------------------------------------------------
template<int OUT_BF16, int RELU>
__global__ __launch_bounds__(256) void gemm_mfma_kernel(
    const unsigned short* __restrict__ A, const unsigned short* __restrict__ Bt,
    const float* __restrict__ bias, const float* __restrict__ resid,
    void* __restrict__ Cout, int M, int N, int K)
{
    __shared__ unsigned short Asm[2][128 * 32];
    __shared__ unsigned short Bsm[2][128 * 32];

    int t = threadIdx.x;
    int lane = t & 63, wv = t >> 6;
    int wm = wv & 1, wn = wv >> 1;
    int l16 = lane & 15, quad = lane >> 4;

    int bm = blockIdx.x * 128;
    int bn = blockIdx.y * 128;

    const unsigned short* Abase = A  + (size_t)bm * K;
    const unsigned short* Bbase = Bt + (size_t)bn * K;

    int fl0 = t, fl1 = 256 + t;
    int r0 = fl0 >> 2, lg0 = (fl0 ^ (fl0 >> 3)) & 3;
    int r1 = fl1 >> 2, lg1 = (fl1 ^ (fl1 >> 3)) & 3;

    f4 acc[4][4] = {};

    GLOBAL_LOAD_LDS16(Abase + (size_t)r0 * K + lg0 * 8, &Asm[0][fl0 * 8]);
    GLOBAL_LOAD_LDS16(Abase + (size_t)r1 * K + lg1 * 8, &Asm[0][fl1 * 8]);
    GLOBAL_LOAD_LDS16(Bbase + (size_t)r0 * K + lg0 * 8, &Bsm[0][fl0 * 8]);
    GLOBAL_LOAD_LDS16(Bbase + (size_t)r1 * K + lg1 * 8, &Bsm[0][fl1 * 8]);
    __syncthreads();

    int nk = K >> 5;
    int cur = 0;
    for (int it = 0; it < nk; ++it) {
        if (it + 1 < nk) {
            int k0 = (it + 1) << 5;
            GLOBAL_LOAD_LDS16(Abase + (size_t)r0 * K + k0 + lg0 * 8, &Asm[cur ^ 1][fl0 * 8]);
            GLOBAL_LOAD_LDS16(Abase + (size_t)r1 * K + k0 + lg1 * 8, &Asm[cur ^ 1][fl1 * 8]);
            GLOBAL_LOAD_LDS16(Bbase + (size_t)r0 * K + k0 + lg0 * 8, &Bsm[cur ^ 1][fl0 * 8]);
            GLOBAL_LOAD_LDS16(Bbase + (size_t)r1 * K + k0 + lg1 * 8, &Bsm[cur ^ 1][fl1 * 8]);
        }

        bf16x8 xf[4], wf[4];
        #pragma unroll
        for (int i = 0; i < 4; i++) {
            int m = wm * 64 + i * 16 + l16;
            int p = (quad ^ (m >> 1)) & 3;
            xf[i] = __builtin_bit_cast(bf16x8, *(const i4*)&Asm[cur][m * 32 + p * 8]);
        }
        #pragma unroll
        for (int j = 0; j < 4; j++) {
            int n = wn * 64 + j * 16 + l16;
            int p = (quad ^ (n >> 1)) & 3;
            wf[j] = __builtin_bit_cast(bf16x8, *(const i4*)&Bsm[cur][n * 32 + p * 8]);
        }
        #pragma unroll
        for (int j = 0; j < 4; j++)
            #pragma unroll
            for (int i = 0; i < 4; i++)
                acc[j][i] = __builtin_amdgcn_mfma_f32_16x16x32_bf16(wf[j], xf[i], acc[j][i], 0, 0, 0);

        __syncthreads();
        cur ^= 1;
    }

    #pragma unroll
    for (int i = 0; i < 4; i++) {
        int rowg = bm + wm * 64 + i * 16 + l16;
        #pragma unroll
        for (int j = 0; j < 4; j++) {
            int colg0 = bn + wn * 64 + j * 16 + quad * 4;
            f4 v = acc[j][i];
            f4 b4 = *(const f4*)&bias[colg0];
            v += b4;
            if (RELU) {
                #pragma unroll
                for (int r = 0; r < 4; r++) v[r] = fmaxf(v[r], 0.f);
            }
            if (resid) {
                f4 r4 = *(const f4*)&resid[(size_t)rowg * N + colg0];
                v += r4;
            }
            if (OUT_BF16) {
                us4 o;
                o.x = f2bf(v[0]); o.y = f2bf(v[1]); o.z = f2bf(v[2]); o.w = f2bf(v[3]);
                *(us4*)((unsigned short*)Cout + (size_t)rowg * N + colg0) = o;
            } else {
                *(f4*)((float*)Cout + (size_t)rowg * N + colg0) = v;
            }
        }
    }
}

// ---------------------------------------------------------------------------
// bf16 MFMA GEMM, 256x128 tile, BK=32, 512 threads (8 waves), dbuf prefetch +
// XOR swizzle. launch_bounds (512,4): VGPR cap 128 (kernel needs ~110; a cap
// of 85 from 6 waves/EU would spill the 64-VGPR accumulator to scratch).
// 48KB LDS; 2 blocks/CU by VGPR. Amortizes B staging over 2x A rows.
// ---------------------------------------------------------------------------
template<int OUT_BF16, int RELU>
__global__ __launch_bounds__(512, 4) void gemm_mfma_m256_kernel(
    const unsigned short* __restrict__ A, const unsigned short* __restrict__ Bt,
    const float* __restrict__ bias, const float* __restrict__ resid,
    void* __restrict__ Cout, int M, int N, int K)
{
    __shared__ unsigned short Asm[2][256 * 32];
    __shared__ unsigned short Bsm[2][128 * 32];

    int t = threadIdx.x;                 // 0..511
    int lane = t & 63, wv = t >> 6;      // 8 waves
    int wm = wv & 3, wn = wv >> 2;       // 4 row-groups x 2 col-groups of 64
    int l16 = lane & 15, quad = lane >> 4;

    int bm = blockIdx.x * 256;
    int bn = blockIdx.y * 128;

    const unsigned short* Abase = A  + (size_t)bm * K;
    const unsigned short* Bbase = Bt + (size_t)bn * K;

    int fa0 = t, fa1 = t + 512;
    int ra0 = fa0 >> 2, la0 = (fa0 ^ (fa0 >> 3)) & 3;
    int ra1 = fa1 >> 2, la1 = (fa1 ^ (fa1 >> 3)) & 3;
    int rb0 = t >> 2,   lb0 = (t ^ (t >> 3)) & 3;

    f4 acc[4][4] = {};

    GLOBAL_LOAD_LDS16(Abase + (size_t)ra0 * K + la0 * 8, &Asm[0][fa0 * 8]);
    GLOBAL_LOAD_LDS16(Abase + (size_t)ra1 * K + la1 * 8, &Asm[0][fa1 * 8]);
    GLOBAL_LOAD_LDS16(Bbase + (size_t)rb0 * K + lb0 * 8, &Bsm[0][t * 8]);
    __syncthreads();

    int nk = K >> 5;
    int cur = 0;
    for (int it = 0; it < nk; ++it) {
        if (it + 1 < nk) {
            int k0 = (it + 1) << 5;
            GLOBAL_LOAD_LDS16(Abase + (size_t)ra0 * K + k0 + la0 * 8, &Asm[cur ^ 1][fa0 * 8]);
            GLOBAL_LOAD_LDS16(Abase + (size_t)ra1 * K + k0 + la1 * 8, &Asm[cur ^ 1][fa1 * 8]);
            GLOBAL_LOAD_LDS16(Bbase + (size_t)rb0 * K + k0 + lb0 * 8, &Bsm[cur ^ 1][t * 8]);
        }

        bf16x8 xf[4], wf[4];
        #pragma unroll
        for (int i = 0; i < 4; i++) {
            int m = wm * 64 + i * 16 + l16;
            int p = (quad ^ (m >> 1)) & 3;
            xf[i] = __builtin_bit_cast(bf16x8, *(const i4*)&Asm[cur][m * 32 + p * 8]);
        }
        #pragma unroll
        for (int j = 0; j < 4; j++) {
            int n = wn * 64 + j * 16 + l16;
            int p = (quad ^ (n >> 1)) & 3;
            wf[j] = __builtin_bit_cast(bf16x8, *(const i4*)&Bsm[cur][n * 32 + p * 8]);
        }
        #pragma unroll
        for (int j = 0; j < 4; j++)
            #pragma unroll
            for (int i = 0; i < 4; i++)
                acc[j][i] = __builtin_amdgcn_mfma_f32_16x16x32_bf16(wf[j], xf[i], acc[j][i], 0, 0, 0);

        __syncthreads();
        cur ^= 1;
    }

    #pragma unroll
    for (int i = 0; i < 4; i++) {
        int rowg = bm + wm * 64 + i * 16 + l16;
        #pragma unroll
        for (int j = 0; j < 4; j++) {
            int colg0 = bn + wn * 64 + j * 16 + quad * 4;
            f4 v = acc[j][i];
            f4 b4 = *(const f4*)&bias[colg0];
            v += b4;
            if (RELU) {
                #pragma unroll
                for (int r = 0; r < 4; r++) v[r] = fmaxf(v[r], 0.f);
            }
            if (resid) {
                f4 r4 = *(const f4*)&resid[(size_t)rowg * N + colg0];
                v += r4;
            }
            if (OUT_BF16) {
                us4 o;
                o.x = f2bf(v[0]); o.y = f2bf(v[1]); o.z = f2bf(v[2]); o.w = f2bf(v[3]);
                *(us4*)((unsigned short*)Cout + (size_t)rowg * N + colg0) = o;
            } else {
                *(f4*)((float*)Cout + (size_t)rowg * N + colg0) = v;
            }
        }
    }
}

// ---------------------------------------------------------------------------
// bf16 MFMA GEMM, 128x64 tile, BK=64, double-buffered prefetch + XOR swizzle.
// LDS 48KB -> 3 blocks/CU (matches 768-block grid for N=768 GEMMs).
// ---------------------------------------------------------------------------
template<int OUT_BF16, int RELU>
__global__ __launch_bounds__(256) void gemm_mfma_n64_kernel(
    const unsigned short* __restrict__ A, const unsigned short* __restrict__ Bt,
    const float* __restrict__ bias, const float* __restrict__ resid,
    void* __restrict__ Cout, int M, int N, int K)
{
    __shared__ unsigned short Asm[2][128 * 64];
    __shared__ unsigned short Bsm[2][64 * 64];

    int t = threadIdx.x;
    int lane = t & 63, wv = t >> 6;
    int wm = wv & 1, wn = wv >> 1;
    int l16 = lane & 15, quad = lane >> 4;

    int bm = blockIdx.x * 128;
    int bn = blockIdx.y * 64;

    const unsigned short* Abase = A  + (size_t)bm * K;
    const unsigned short* Bbase = Bt + (size_t)bn * K;

    int ar[4], alg[4], br[2], blg[2];
    #pragma unroll
    for (int i = 0; i < 4; i++) {
        int fl = t + i * 256;
        ar[i] = fl >> 3; alg[i] = (fl ^ (fl >> 3)) & 7;
    }
    #pragma unroll
    for (int i = 0; i < 2; i++) {
        int fl = t + i * 256;
        br[i] = fl >> 3; blg[i] = (fl ^ (fl >> 3)) & 7;
    }

    f4 acc[2][4] = {};

    #pragma unroll
    for (int i = 0; i < 4; i++)
        GLOBAL_LOAD_LDS16(Abase + (size_t)ar[i] * K + alg[i] * 8, &Asm[0][(t + i * 256) * 8]);
    #pragma unroll
    for (int i = 0; i < 2; i++)
        GLOBAL_LOAD_LDS16(Bbase + (size_t)br[i] * K + blg[i] * 8, &Bsm[0][(t + i * 256) * 8]);
    __syncthreads();

    int nk = K >> 6;
    int cur = 0;
    for (int it = 0; it < nk; ++it) {
        if (it + 1 < nk) {
            int k0 = (it + 1) << 6;
            #pragma unroll
            for (int i = 0; i < 4; i++)
                GLOBAL_LOAD_LDS16(Abase + (size_t)ar[i] * K + k0 + alg[i] * 8, &Asm[cur ^ 1][(t + i * 256) * 8]);
            #pragma unroll
            for (int i = 0; i < 2; i++)
                GLOBAL_LOAD_LDS16(Bbase + (size_t)br[i] * K + k0 + blg[i] * 8, &Bsm[cur ^ 1][(t + i * 256) * 8]);
        }

        #pragma unroll
        for (int kk = 0; kk < 2; kk++) {
            bf16x8 xf[4], wf[2];
            #pragma unroll
            for (int i = 0; i < 4; i++) {
                int m = wm * 64 + i * 16 + l16;
                int p = ((kk * 4 + quad) ^ (m & 7)) & 7;
                xf[i] = __builtin_bit_cast(bf16x8, *(const i4*)&Asm[cur][m * 64 + p * 8]);
            }
            #pragma unroll
            for (int j = 0; j < 2; j++) {
                int n = wn * 32 + j * 16 + l16;
                int p = ((kk * 4 + quad) ^ (n & 7)) & 7;
                wf[j] = __builtin_bit_cast(bf16x8, *(const i4*)&Bsm[cur][n * 64 + p * 8]);
            }
            #pragma unroll
            for (int j = 0; j < 2; j++)
                #pragma unroll
                for (int i = 0; i < 4; i++)
                    acc[j][i] = __builtin_amdgcn_mfma_f32_16x16x32_bf16(wf[j], xf[i], acc[j][i], 0, 0, 0);
        }

        __syncthreads();
        cur ^= 1;
    }

    #pragma unroll
    for (int i = 0; i < 4; i++) {
        int rowg = bm + wm * 64 + i * 16 + l16;
        #pragma unroll
        for (int j = 0; j < 2; j++) {
            int colg0 = bn + wn * 32 + j * 16 + quad * 4;
            f4 v = acc[j][i];
            f4 b4 = *(const f4*)&bias[colg0];
            v += b4;
            if (RELU) {
                #pragma unroll
                for (int r = 0; r < 4; r++) v[r] = fmaxf(v[r], 0.f);
            }
            if (resid) {
                f4 r4 = *(const f4*)&resid[(size_t)rowg * N + colg0];
                v += r4;
            }
            if (OUT_BF16) {
                us4 o;
                o.x = f2bf(v[0]); o.y = f2bf(v[1]); o.z = f2bf(v[2]); o.w = f2bf(v[3]);
                *(us4*)((unsigned short*)Cout + (size_t)rowg * N + colg0) = o;
            } else {
                *(f4*)((float*)Cout + (size_t)rowg * N + colg0) = v;
            }
        }
    }
}

// ---------------------------------------------------------------------------
// V transpose + q2/k2 norms fused. Per block (bh,kt): 64 tokens of one head.
// V -> padded [96][72] tile; q2 = sum(q~^2) (carries cexp^2), k2 = 0.25*sum(k~^2).
// ---------------------------------------------------------------------------
__global__ __launch_bounds__(256) void vtrans_norms_kernel(
    const unsigned short* __restrict__ qkv, unsigned short* __restrict__ vt,
    float* __restrict__ q2g, float* __restrict__ k2g)
{
    __shared__ unsigned short Vl[64][100];
    int blk = blockIdx.x;          // bh*16 + kt
    int bh = blk >> 4, kt = blk & 15;
    int b = bh >> 3, hh = bh & 7;
    int t = threadIdx.x;
    int key = t >> 2, qc = t & 3;
    const unsigned short* tok = qkv + ((size_t)(b * S_ + kt * 64 + key)) * QKVW + hh * DH_;
    // norms: 4 threads per token, 24 q + 24 k shorts each
    float qs = 0.f, ks = 0.f;
    #pragma unroll
    for (int i = 0; i < 3; i++) {
        us8 qv = *(const us8*)(tok + (qc * 3 + i) * 8);
        us8 kv = *(const us8*)(tok + 768 + (qc * 3 + i) * 8);
        #pragma unroll
        for (int e = 0; e < 8; e++) {
            float qf = bf2f(qv[e]), kf = bf2f(kv[e]);
            qs += qf * qf; ks += kf * kf;
        }
    }
    qs += __shfl_xor(qs, 1, 4); qs += __shfl_xor(qs, 2, 4);
    ks += __shfl_xor(ks, 1, 4); ks += __shfl_xor(ks, 2, 4);
    if (qc == 0) {
        int idx = (b * H_ + hh) * S_ + kt * 64 + key;
        q2g[idx] = qs; k2g[idx] = ks * 0.25f;
    }
    // V transpose
    const unsigned short* src = tok + 1536;
    #pragma unroll
    for (int i = 0; i < 3; i++) {
        int chunk = qc + i * 4;            // 0..11, 8 shorts each
        us8 v = *(const us8*)(src + chunk * 8);
        #pragma unroll
        for (int e = 0; e < 8; e++) Vl[key][chunk * 8 + e] = v[e];
    }
    __syncthreads();
    unsigned short* dst = vt + (size_t)blk * 7168;
    #pragma unroll
    for (int r = 0; r < 3; r++) {
        int c = r * 256 + t;               // 0..767
        int vd = c >> 3, kc = c & 7;
        us8 o;
        #pragma unroll
        for (int j = 0; j < 8; j++) o[j] = Vl[kc * 8 + j][vd];
        *(us8*)(dst + vd * 72 + kc * 8) = o;
    }
}

// ---------------------------------------------------------------------------
// MFMA flash attention, L2 distances in cexp^2-scaled space: the QK MFMA with
// C-init (q2+k2) emits d2' = cexp^2*d2 directly; p = exp2(-sqrt(|d2'|)) -- no
// per-score multiply, fabs folds into the sqrt input modifier. k2 staged
// through LDS inside the double-buffered prefetch (no per-iter global stall).
// 2 q-frags/wave; K chunk-major conflict-free; XCD swizzle: one batch per XCD.
// ---------------------------------------------------------------------------
__global__ __launch_bounds__(256, 2) void attn_mfma_kernel(
    const unsigned short* __restrict__ qkv,
    const unsigned short* __restrict__ vt,
    const float* __restrict__ q2g, const float* __restrict__ k2g,
    unsigned short* __restrict__ outb)
{
    __shared__ unsigned short Klds[2][6144];     // chunk-major: [dc 0..11][key 0..63][8]
    __shared__ unsigned short Vlds[2][7168];     // [vdim][72]
    __shared__ float k2lds[2][64];               // staged k2 tile
    __shared__ unsigned short Plds[4][2][16 * 72];  // per-wave per-frag [qrow][key]

    int t = threadIdx.x;
    int lane = t & 63, w = t >> 6;
    int l16 = lane & 15, quad = lane >> 4;

    int bid = blockIdx.x;
    int slot = bid >> 3;
    int bh = (bid & 7) * 8 + (slot >> 3);
    int qt = slot & 7;
    int b = bh >> 3, hh = bh & 7;

    int qrowW = qt * 128 + w * 32;    // this wave's first q-row (32 rows, 2 frags)

    const unsigned short* qb = qkv + ((size_t)(b * S_ + qrowW)) * QKVW + hh * DH_;
    bf16x8 qf[2][3];
    #pragma unroll
    for (int f = 0; f < 2; f++)
        #pragma unroll
        for (int d = 0; d < 3; d++)
            qf[f][d] = __builtin_bit_cast(bf16x8,
                *(const i4*)(qb + (size_t)(f * 16 + l16) * QKVW + d * 32 + quad * 8));

    float q2n[2];
    #pragma unroll
    for (int f = 0; f < 2; f++)
        q2n[f] = q2g[bh * S_ + qrowW + f * 16 + l16];

    float lsum0 = 0.f, lsum1 = 0.f;
    f4 Oacc[2][6] = {};

    const unsigned short* kgb = qkv + ((size_t)(b * S_)) * QKVW + 768 + hh * DH_;
    const unsigned short* vgb0 = vt + (size_t)(bh * 16) * 7168;
    const float* k2base = k2g + bh * S_;

    int kkey = t & 63;
    #define ATTN_STAGE(bb, itv)                                                   \
        {                                                                         \
            _Pragma("unroll")                                                     \
            for (int r = 0; r < 3; r++) {                                         \
                int c = r * 256 + t;                                              \
                int dc = c >> 6;                                                  \
                GLOBAL_LOAD_LDS16(kgb + ((size_t)((itv) * 64 + kkey)) * QKVW + dc * 8, \
                                  &Klds[bb][c * 8]);                              \
            }                                                                     \
            const unsigned short* vgb = vgb0 + (size_t)(itv) * 7168;              \
            _Pragma("unroll")                                                     \
            for (int r = 0; r < 3; r++)                                           \
                GLOBAL_LOAD_LDS16(vgb + (r * 256 + t) * 8, &Vlds[bb][(r * 256 + t) * 8]); \
            if (t < 128)                                                          \
                GLOBAL_LOAD_LDS16(vgb + (768 + t) * 8, &Vlds[bb][(768 + t) * 8]); \
            if (t < 16)                                                           \
                GLOBAL_LOAD_LDS16(k2base + (itv) * 64 + t * 4, &k2lds[bb][t * 4]); \
        }

    ATTN_STAGE(0, 0);
    __syncthreads();

    for (int it = 0; it < 16; it++) {
        int cur = it & 1;
        if (it) __syncthreads();          // prev prefetch landed; prev reads done
        if (it + 1 < 16) ATTN_STAGE(cur ^ 1, it + 1);   // overlap with compute below

        // S^T = K' . Q^T + (q2+k2) : C-frag col(l16)=qrow, row(quad*4+r)=key
        const unsigned short* kB = &Klds[cur][quad * 512 + l16 * 8];
        #pragma unroll
        for (int kt2 = 0; kt2 < 4; kt2++) {
            const unsigned short* kp = kB + kt2 * 128;
            bf16x8 kf0 = __builtin_bit_cast(bf16x8, *(const i4*)(kp));
            bf16x8 kf1 = __builtin_bit_cast(bf16x8, *(const i4*)(kp + 2048));
            bf16x8 kf2 = __builtin_bit_cast(bf16x8, *(const i4*)(kp + 4096));
            f4 kk = *(const f4*)&k2lds[cur][kt2 * 16 + quad * 4];
            #pragma unroll
            for (int f = 0; f < 2; f++) {
                f4 a = {kk[0] + q2n[f], kk[1] + q2n[f], kk[2] + q2n[f], kk[3] + q2n[f]};
                __builtin_amdgcn_s_setprio(1);
                a = __builtin_amdgcn_mfma_f32_16x16x32_bf16(kf0, qf[f][0], a, 0, 0, 0);
                a = __builtin_amdgcn_mfma_f32_16x16x32_bf16(kf1, qf[f][1], a, 0, 0, 0);
                a = __builtin_amdgcn_mfma_f32_16x16x32_bf16(kf2, qf[f][2], a, 0, 0, 0);
                __builtin_amdgcn_s_setprio(0);
                #pragma unroll
                for (int r2 = 0; r2 < 4; r2++) {
                    float p = exp2f(-__builtin_amdgcn_sqrtf(__builtin_fabsf(a[r2])));
                    if (f == 0) lsum0 += p; else lsum1 += p;
                    a[r2] = p;
                }
                unsigned int plo, phi;
                asm("v_cvt_pk_bf16_f32 %0, %1, %2" : "=v"(plo) : "v"(a[0]), "v"(a[1]));
                asm("v_cvt_pk_bf16_f32 %0, %1, %2" : "=v"(phi) : "v"(a[2]), "v"(a[3]));
                uint2 pkd; pkd.x = plo; pkd.y = phi;
                *(uint2*)&Plds[w][f][l16 * 72 + kt2 * 16 + quad * 4] = pkd;
            }
        }
        // O += P . V (no rescale needed: fixed shift)
        bf16x8 pa[2][2];
        #pragma unroll
        for (int f = 0; f < 2; f++) {
            pa[f][0] = __builtin_bit_cast(bf16x8, *(const i4*)&Plds[w][f][l16 * 72 + quad * 8]);
            pa[f][1] = __builtin_bit_cast(bf16x8, *(const i4*)&Plds[w][f][l16 * 72 + 32 + quad * 8]);
        }
        __builtin_amdgcn_s_setprio(1);
        #pragma unroll
        for (int vtl = 0; vtl < 6; vtl++) {
            bf16x8 vf0 = __builtin_bit_cast(bf16x8, *(const i4*)&Vlds[cur][(vtl * 16 + l16) * 72 + quad * 8]);
            bf16x8 vf1 = __builtin_bit_cast(bf16x8, *(const i4*)&Vlds[cur][(vtl * 16 + l16) * 72 + 32 + quad * 8]);
            #pragma unroll
            for (int f = 0; f < 2; f++) {
                Oacc[f][vtl] = __builtin_amdgcn_mfma_f32_16x16x32_bf16(pa[f][0], vf0, Oacc[f][vtl], 0, 0, 0);
                Oacc[f][vtl] = __builtin_amdgcn_mfma_f32_16x16x32_bf16(pa[f][1], vf1, Oacc[f][vtl], 0, 0, 0);
            }
        }
        __builtin_amdgcn_s_setprio(0);
    }
    // deferred l-reduction over the 4 quads, per frag
    #pragma unroll
    for (int f = 0; f < 2; f++) {
        float ls = (f == 0) ? lsum0 : lsum1;
        ls += __shfl_xor(ls, 16, 64);
        ls += __shfl_xor(ls, 32, 64);
        float inv_l = 1.f / ls;
        f4 iv;
        #pragma unroll
        for (int r2 = 0; r2 < 4; r2++)
            iv[r2] = __shfl(inv_l, quad * 4 + r2, 64);
        #pragma unroll
        for (int vtl = 0; vtl < 6; vtl++)
            #pragma unroll
            for (int r2 = 0; r2 < 4; r2++) {
                int row = b * S_ + qrowW + f * 16 + quad * 4 + r2;
                outb[(size_t)row * D_ + hh * DH_ + vtl * 16 + l16] = f2bf(Oacc[f][vtl][r2] * iv[r2]);
            }
    }
    #undef ATTN_STAGE
}

// ---------------------------------------------------------------------------
extern "C" void kernel_launch(void* const* d_in, const int* in_sizes, int n_in,
                              void* d_out, int out_size, void* d_ws, size_t ws_size,
                              hipStream_t stream)
{
    const float* h    = (const float*)d_in[0];
    const float* x    = (const float*)d_in[1];
    const float* g1   = (const float*)d_in[2];
    const float* be1  = (const float*)d_in[3];
    const float* ln1w = (const float*)d_in[4];
    const float* ln1b = (const float*)d_in[5];
    const float* g2   = (const float*)d_in[6];
    const float* be2  = (const float*)d_in[7];
    const float* ln2w = (const float*)d_in[8];
    const float* ln2b = (const float*)d_in[9];
    const float* Wq   = (const float*)d_in[10];
    const float* bq   = (const float*)d_in[11];
    const float* Wk   = (const float*)d_in[12];
    const float* bk   = (const float*)d_in[13];
    const float* Wv   = (const float*)d_in[14];
    const float* bv   = (const float*)d_in[15];
    const float* Wo   = (const float*)d_in[16];
    const float* bo   = (const float*)d_in[17];
    const float* W1   = (const float*)d_in[18];
    const float* b1   = (const float*)d_in[19];
    const float* W2   = (const float*)d_in[20];
    const float* b2   = (const float*)d_in[21];

    float* out = (float*)d_out;
    char* wsb = (char*)d_ws;
    const size_t ND = (size_t)NTOK * D_;

    size_t off = 0;
    unsigned short* W1t = (unsigned short*)(wsb + off); off += 4718592;       // [3072][768]
    unsigned short* W2t = (unsigned short*)(wsb + off); off += 4718592;       // [768][3072]
    float* bqkv = (float*)(wsb + off);                  off += 16384;
    float* htmp = (float*)(wsb + off);                  off += ND * 4;        // fp32
    float* q2g  = (float*)(wsb + off);                  off += (size_t)B_ * H_ * S_ * 4;
    float* k2g  = (float*)(wsb + off);                  off += (size_t)B_ * H_ * S_ * 4;
    unsigned short* h2b = (unsigned short*)(wsb + off); off += ND * 2;        // SLN2 out
    // ---- dead pool (all dead before the MLP) ----
    size_t pool0 = off;
    unsigned short* Wqkvt = (unsigned short*)(wsb + off); off += 3538944;     // [2304][768]
    unsigned short* Wot   = (unsigned short*)(wsb + off); off += 1179648;     // [768][768]
    unsigned short* h1b   = (unsigned short*)(wsb + off); off += ND * 2;      // alias: attnb
    unsigned short* vtg   = (unsigned short*)(wsb + off); off += (size_t)1024 * 14336;
    unsigned short* qkvb  = (unsigned short*)(wsb + off); off += (size_t)NTOK * QKVW * 2;
    unsigned short* attnb   = h1b;
    unsigned short* hiddenb = (unsigned short*)(wsb + pool0);  // [8192][3072] bf16 overlay

    // --- weight prep: single merged kernel (6 transposes + bias concat) ---
    prep_all_kernel<<<6921, dim3(32, 8), 0, stream>>>(
        Wq, Wk, Wv, Wo, W1, W2, bq, bk, bv, Wqkvt, Wot, W1t, W2t, bqkv);

    // 1. SLN1 -> h1b (bf16), copy x -> out[0:ND]
    sln_kernel<<<NTOK, 192, 0, stream>>>(h, x, g1, be1, ln1w, ln1b, h1b, out);

    // 2. fused QKV GEMM: [8192,768] @ [768,2304] -> qkvb bf16 (q,k parts pre-scaled)
    gemm_mfma_kernel<1, 0><<<dim3(NTOK/128, QKVW/128), 256, 0, stream>>>(
        h1b, Wqkvt, bqkv, nullptr, qkvb, NTOK, QKVW, D_);

    // 3. V transpose tiles + q2/k2 norms (fused)
    vtrans_norms_kernel<<<1024, 256, 0, stream>>>(qkvb, vtg, q2g, k2g);

    // 4. MFMA attention -> attnb bf16 (512 blocks: 64 bh x 8 q-tiles of 128)
    attn_mfma_kernel<<<512, 256, 0, stream>>>(qkvb, vtg, q2g, k2g, attnb);

    // 5. Wo projection + residual h -> htmp fp32 (128x64 tiles: 768 blocks)
    gemm_mfma_n64_kernel<0, 0><<<dim3(NTOK/128, D_/64), 256, 0, stream>>>(
        attnb, Wot, bo, h, htmp, NTOK, D_, D_);

    // 6. SLN2 -> h2b bf16
    sln_kernel<<<NTOK, 192, 0, stream>>>(htmp, x, g2, be2, ln2w, ln2b, h2b, nullptr);

    // 7. MLP: W1 on 256x128 tiles, W2 on 128x64
    gemm_mfma_m256_kernel<1, 1><<<dim3(NTOK/256, DFF_/128), 512, 0, stream>>>(
        h2b, W1t, b1, nullptr, hiddenb, NTOK, DFF_, D_);
    gemm_mfma_n64_kernel<0, 0><<<dim3(NTOK/128, D_/64), 256, 0, stream>>>(
        hiddenb, W2t, b2, htmp, out + ND, NTOK, D_, DFF_);

    (void)in_sizes; (void)n_in; (void)out_size; (void)ws_size;
}

// Round 6
// 404.741 us; speedup vs baseline: 1.0607x; 1.0020x over previous
//
#include <hip/hip_runtime.h>
#include <math.h>

#define B_ 8
#define S_ 1024
#define D_ 768
#define H_ 8
#define DH_ 96
#define DFF_ 3072
#define NTOK (B_*S_)
#define QKVW 2304            // fused q|k|v width
#define EPS_ 1e-5f
#define CEXP_ 0.14724445f    // log2(e)/sqrt(96), folded into Wq/Wk scaling

typedef __attribute__((ext_vector_type(4))) float f4;
typedef __attribute__((ext_vector_type(4))) int i4;
typedef __attribute__((ext_vector_type(8))) __bf16 bf16x8;
typedef __attribute__((ext_vector_type(4))) unsigned short us4;
typedef __attribute__((ext_vector_type(8))) unsigned short us8;

static __device__ __forceinline__ unsigned short f2bf(float f) {
    unsigned int u = __builtin_bit_cast(unsigned int, f);
    u += 0x7fffu + ((u >> 16) & 1u);
    return (unsigned short)(u >> 16);
}
static __device__ __forceinline__ float bf2f(unsigned short u) {
    unsigned int x = ((unsigned int)u) << 16;
    return __builtin_bit_cast(float, x);
}

#define GLOBAL_LOAD_LDS16(g, l) \
    __builtin_amdgcn_global_load_lds((const __attribute__((address_space(1))) unsigned int*)(g), \
                                     (__attribute__((address_space(3))) unsigned int*)(l), 16, 0, 0)

// ---------------------------------------------------------------------------
// SLN: out_bf16 = bf16( x * (gamma * LayerNorm(h) + beta) ); optional x copy (fp32)
// ---------------------------------------------------------------------------
__global__ __launch_bounds__(192) void sln_kernel(
    const float* __restrict__ h, const float* __restrict__ x,
    const float* __restrict__ gamma, const float* __restrict__ beta,
    const float* __restrict__ w, const float* __restrict__ bvec,
    unsigned short* __restrict__ out_bf, float* __restrict__ xcopy)
{
    int row = blockIdx.x;
    int t = threadIdx.x;
    const float4* h4 = (const float4*)(h + (size_t)row * D_);
    const float4* x4 = (const float4*)(x + (size_t)row * D_);
    float4 hv = h4[t];
    float s  = hv.x + hv.y + hv.z + hv.w;
    float ss = hv.x*hv.x + hv.y*hv.y + hv.z*hv.z + hv.w*hv.w;
    #pragma unroll
    for (int off = 32; off > 0; off >>= 1) {
        s  += __shfl_down(s, off);
        ss += __shfl_down(ss, off);
    }
    __shared__ float red[2][3];
    int wid = t >> 6;
    if ((t & 63) == 0) { red[0][wid] = s; red[1][wid] = ss; }
    __syncthreads();
    float sum   = red[0][0] + red[0][1] + red[0][2];
    float sumsq = red[1][0] + red[1][1] + red[1][2];
    float mu  = sum * (1.0f / D_);
    float var = sumsq * (1.0f / D_) - mu * mu;
    float rstd = rsqrtf(var + EPS_);
    float g = gamma[0], be = beta[0];
    float4 wv = ((const float4*)w)[t];
    float4 bv = ((const float4*)bvec)[t];
    float4 xv = x4[t];
    us4 o;
    o.x = f2bf(xv.x * (g * ((hv.x - mu) * rstd * wv.x + bv.x) + be));
    o.y = f2bf(xv.y * (g * ((hv.y - mu) * rstd * wv.y + bv.y) + be));
    o.z = f2bf(xv.z * (g * ((hv.z - mu) * rstd * wv.z + bv.z) + be));
    o.w = f2bf(xv.w * (g * ((hv.w - mu) * rstd * wv.w + bv.w) + be));
    *(us4*)(out_bf + (size_t)row * D_ + t * 4) = o;
    if (xcopy) ((float4*)(xcopy + (size_t)row * D_))[t] = xv;
}

// ---------------------------------------------------------------------------
// Merged weight prep: all 6 transposes (fp32->bf16, [K][N]->[N][K]) + bias concat
// Wq/bq scaled by cexp, Wk/bk by -2*cexp: the attention QK^T MFMA then emits
// cexp^2 * (-2 q.k); q2/k2 computed from the scaled values carry cexp^2 too,
// so d2' = cexp^2 * d2 and p = exp2(-sqrt(d2')) with no per-score multiply.
// ---------------------------------------------------------------------------
__global__ __launch_bounds__(256) void prep_all_kernel(
    const float* __restrict__ Wq, const float* __restrict__ Wk,
    const float* __restrict__ Wv, const float* __restrict__ Wo,
    const float* __restrict__ W1, const float* __restrict__ W2,
    const float* __restrict__ bq, const float* __restrict__ bk, const float* __restrict__ bv,
    unsigned short* __restrict__ Wqkvt, unsigned short* __restrict__ Wot,
    unsigned short* __restrict__ W1t, unsigned short* __restrict__ W2t,
    float* __restrict__ bqkv)
{
    int id = blockIdx.x;
    int tx = threadIdx.x, ty = threadIdx.y;
    if (id >= 6912) {   // bias concat: 9 blocks x 256 threads
        int i = (id - 6912) * 256 + ty * 32 + tx;
        if (i < QKVW) {
            float v = (i < 768) ? CEXP_ * bq[i]
                    : (i < 1536) ? -2.f * CEXP_ * bk[i - 768] : bv[i - 1536];
            bqkv[i] = v;
        }
        return;
    }
    const float* in; unsigned short* out; int K, N, nbx, rel;
    float scl = 1.f;
    if (id < 1728)      { int m = id / 576; rel = id % 576;
                          in = (m == 0) ? Wq : (m == 1) ? Wk : Wv;
                          if (m == 0) scl = CEXP_;
                          if (m == 1) scl = -2.f * CEXP_;
                          out = Wqkvt + (size_t)m * 768 * 768; K = 768; N = 768; nbx = 24; }
    else if (id < 2304) { rel = id - 1728; in = Wo; out = Wot;  K = 768;  N = 768;  nbx = 24; }
    else if (id < 4608) { rel = id - 2304; in = W1; out = W1t;  K = 768;  N = 3072; nbx = 96; }
    else                { rel = id - 4608; in = W2; out = W2t;  K = 3072; N = 768;  nbx = 24; }
    int n0 = (rel % nbx) * 32, k0 = (rel / nbx) * 32;
    __shared__ float tile[32][33];
    #pragma unroll
    for (int r = 0; r < 4; r++)
        tile[ty + r * 8][tx] = in[(size_t)(k0 + ty + r * 8) * N + n0 + tx];
    __syncthreads();
    #pragma unroll
    for (int r = 0; r < 4; r++)
        out[(size_t)(n0 + ty + r * 8) * K + k0 + tx] = f2bf(scl * tile[tx][ty + r * 8]);
}

// ---------------------------------------------------------------------------
// bf16 MFMA GEMM, 128x128 tile, BK=32, double-buffered prefetch (T3 2-phase),
// XOR chunk-swizzled LDS (pre-swizzled global source, linear gload_lds dest).
// Measured 608 TF at M=8192 shapes: at the 2-phase structural ceiling (m233).
// NOTE: a 256x128/512-thread variant was tried (R5) and regressed to 545 TF:
// ~116 effective VGPR -> 2 blocks/CU vs the 768-block grid's 3/CU need ->
// ragged 1.5-pass tail. 128x128 at 5 blocks/CU (LDS-limited) wins.
// ---------------------------------------------------------------------------
template<int OUT_BF16, int RELU>
__global__ __launch_bounds__(256) void gemm_mfma_kernel(
    const unsigned short* __restrict__ A, const unsigned short* __restrict__ Bt,
    const float* __restrict__ bias, const float* __restrict__ resid,
    void* __restrict__ Cout, int M, int N, int K)
{
    __shared__ unsigned short Asm[2][128 * 32];
    __shared__ unsigned short Bsm[2][128 * 32];

    int t = threadIdx.x;
    int lane = t & 63, wv = t >> 6;
    int wm = wv & 1, wn = wv >> 1;
    int l16 = lane & 15, quad = lane >> 4;

    int bm = blockIdx.x * 128;
    int bn = blockIdx.y * 128;

    const unsigned short* Abase = A  + (size_t)bm * K;
    const unsigned short* Bbase = Bt + (size_t)bn * K;

    int fl0 = t, fl1 = 256 + t;
    int r0 = fl0 >> 2, lg0 = (fl0 ^ (fl0 >> 3)) & 3;
    int r1 = fl1 >> 2, lg1 = (fl1 ^ (fl1 >> 3)) & 3;

    f4 acc[4][4] = {};

    GLOBAL_LOAD_LDS16(Abase + (size_t)r0 * K + lg0 * 8, &Asm[0][fl0 * 8]);
    GLOBAL_LOAD_LDS16(Abase + (size_t)r1 * K + lg1 * 8, &Asm[0][fl1 * 8]);
    GLOBAL_LOAD_LDS16(Bbase + (size_t)r0 * K + lg0 * 8, &Bsm[0][fl0 * 8]);
    GLOBAL_LOAD_LDS16(Bbase + (size_t)r1 * K + lg1 * 8, &Bsm[0][fl1 * 8]);
    __syncthreads();

    int nk = K >> 5;
    int cur = 0;
    for (int it = 0; it < nk; ++it) {
        if (it + 1 < nk) {
            int k0 = (it + 1) << 5;
            GLOBAL_LOAD_LDS16(Abase + (size_t)r0 * K + k0 + lg0 * 8, &Asm[cur ^ 1][fl0 * 8]);
            GLOBAL_LOAD_LDS16(Abase + (size_t)r1 * K + k0 + lg1 * 8, &Asm[cur ^ 1][fl1 * 8]);
            GLOBAL_LOAD_LDS16(Bbase + (size_t)r0 * K + k0 + lg0 * 8, &Bsm[cur ^ 1][fl0 * 8]);
            GLOBAL_LOAD_LDS16(Bbase + (size_t)r1 * K + k0 + lg1 * 8, &Bsm[cur ^ 1][fl1 * 8]);
        }

        bf16x8 xf[4], wf[4];
        #pragma unroll
        for (int i = 0; i < 4; i++) {
            int m = wm * 64 + i * 16 + l16;
            int p = (quad ^ (m >> 1)) & 3;
            xf[i] = __builtin_bit_cast(bf16x8, *(const i4*)&Asm[cur][m * 32 + p * 8]);
        }
        #pragma unroll
        for (int j = 0; j < 4; j++) {
            int n = wn * 64 + j * 16 + l16;
            int p = (quad ^ (n >> 1)) & 3;
            wf[j] = __builtin_bit_cast(bf16x8, *(const i4*)&Bsm[cur][n * 32 + p * 8]);
        }
        #pragma unroll
        for (int j = 0; j < 4; j++)
            #pragma unroll
            for (int i = 0; i < 4; i++)
                acc[j][i] = __builtin_amdgcn_mfma_f32_16x16x32_bf16(wf[j], xf[i], acc[j][i], 0, 0, 0);

        __syncthreads();
        cur ^= 1;
    }

    #pragma unroll
    for (int i = 0; i < 4; i++) {
        int rowg = bm + wm * 64 + i * 16 + l16;
        #pragma unroll
        for (int j = 0; j < 4; j++) {
            int colg0 = bn + wn * 64 + j * 16 + quad * 4;
            f4 v = acc[j][i];
            f4 b4 = *(const f4*)&bias[colg0];
            v += b4;
            if (RELU) {
                #pragma unroll
                for (int r = 0; r < 4; r++) v[r] = fmaxf(v[r], 0.f);
            }
            if (resid) {
                f4 r4 = *(const f4*)&resid[(size_t)rowg * N + colg0];
                v += r4;
            }
            if (OUT_BF16) {
                us4 o;
                o.x = f2bf(v[0]); o.y = f2bf(v[1]); o.z = f2bf(v[2]); o.w = f2bf(v[3]);
                *(us4*)((unsigned short*)Cout + (size_t)rowg * N + colg0) = o;
            } else {
                *(f4*)((float*)Cout + (size_t)rowg * N + colg0) = v;
            }
        }
    }
}

// ---------------------------------------------------------------------------
// bf16 MFMA GEMM, 128x64 tile, BK=64, double-buffered prefetch + XOR swizzle.
// LDS 48KB -> 3 blocks/CU (matches 768-block grid for N=768 GEMMs).
// ---------------------------------------------------------------------------
template<int OUT_BF16, int RELU>
__global__ __launch_bounds__(256) void gemm_mfma_n64_kernel(
    const unsigned short* __restrict__ A, const unsigned short* __restrict__ Bt,
    const float* __restrict__ bias, const float* __restrict__ resid,
    void* __restrict__ Cout, int M, int N, int K)
{
    __shared__ unsigned short Asm[2][128 * 64];
    __shared__ unsigned short Bsm[2][64 * 64];

    int t = threadIdx.x;
    int lane = t & 63, wv = t >> 6;
    int wm = wv & 1, wn = wv >> 1;
    int l16 = lane & 15, quad = lane >> 4;

    int bm = blockIdx.x * 128;
    int bn = blockIdx.y * 64;

    const unsigned short* Abase = A  + (size_t)bm * K;
    const unsigned short* Bbase = Bt + (size_t)bn * K;

    int ar[4], alg[4], br[2], blg[2];
    #pragma unroll
    for (int i = 0; i < 4; i++) {
        int fl = t + i * 256;
        ar[i] = fl >> 3; alg[i] = (fl ^ (fl >> 3)) & 7;
    }
    #pragma unroll
    for (int i = 0; i < 2; i++) {
        int fl = t + i * 256;
        br[i] = fl >> 3; blg[i] = (fl ^ (fl >> 3)) & 7;
    }

    f4 acc[2][4] = {};

    #pragma unroll
    for (int i = 0; i < 4; i++)
        GLOBAL_LOAD_LDS16(Abase + (size_t)ar[i] * K + alg[i] * 8, &Asm[0][(t + i * 256) * 8]);
    #pragma unroll
    for (int i = 0; i < 2; i++)
        GLOBAL_LOAD_LDS16(Bbase + (size_t)br[i] * K + blg[i] * 8, &Bsm[0][(t + i * 256) * 8]);
    __syncthreads();

    int nk = K >> 6;
    int cur = 0;
    for (int it = 0; it < nk; ++it) {
        if (it + 1 < nk) {
            int k0 = (it + 1) << 6;
            #pragma unroll
            for (int i = 0; i < 4; i++)
                GLOBAL_LOAD_LDS16(Abase + (size_t)ar[i] * K + k0 + alg[i] * 8, &Asm[cur ^ 1][(t + i * 256) * 8]);
            #pragma unroll
            for (int i = 0; i < 2; i++)
                GLOBAL_LOAD_LDS16(Bbase + (size_t)br[i] * K + k0 + blg[i] * 8, &Bsm[cur ^ 1][(t + i * 256) * 8]);
        }

        #pragma unroll
        for (int kk = 0; kk < 2; kk++) {
            bf16x8 xf[4], wf[2];
            #pragma unroll
            for (int i = 0; i < 4; i++) {
                int m = wm * 64 + i * 16 + l16;
                int p = ((kk * 4 + quad) ^ (m & 7)) & 7;
                xf[i] = __builtin_bit_cast(bf16x8, *(const i4*)&Asm[cur][m * 64 + p * 8]);
            }
            #pragma unroll
            for (int j = 0; j < 2; j++) {
                int n = wn * 32 + j * 16 + l16;
                int p = ((kk * 4 + quad) ^ (n & 7)) & 7;
                wf[j] = __builtin_bit_cast(bf16x8, *(const i4*)&Bsm[cur][n * 64 + p * 8]);
            }
            #pragma unroll
            for (int j = 0; j < 2; j++)
                #pragma unroll
                for (int i = 0; i < 4; i++)
                    acc[j][i] = __builtin_amdgcn_mfma_f32_16x16x32_bf16(wf[j], xf[i], acc[j][i], 0, 0, 0);
        }

        __syncthreads();
        cur ^= 1;
    }

    #pragma unroll
    for (int i = 0; i < 4; i++) {
        int rowg = bm + wm * 64 + i * 16 + l16;
        #pragma unroll
        for (int j = 0; j < 2; j++) {
            int colg0 = bn + wn * 32 + j * 16 + quad * 4;
            f4 v = acc[j][i];
            f4 b4 = *(const f4*)&bias[colg0];
            v += b4;
            if (RELU) {
                #pragma unroll
                for (int r = 0; r < 4; r++) v[r] = fmaxf(v[r], 0.f);
            }
            if (resid) {
                f4 r4 = *(const f4*)&resid[(size_t)rowg * N + colg0];
                v += r4;
            }
            if (OUT_BF16) {
                us4 o;
                o.x = f2bf(v[0]); o.y = f2bf(v[1]); o.z = f2bf(v[2]); o.w = f2bf(v[3]);
                *(us4*)((unsigned short*)Cout + (size_t)rowg * N + colg0) = o;
            } else {
                *(f4*)((float*)Cout + (size_t)rowg * N + colg0) = v;
            }
        }
    }
}

// ---------------------------------------------------------------------------
// V transpose + q2/k2 norms fused. Per block (bh,kt): 64 tokens of one head.
// V -> padded [96][72] tile; q2 = sum(q~^2) (carries cexp^2), k2 = 0.25*sum(k~^2).
// ---------------------------------------------------------------------------
__global__ __launch_bounds__(256) void vtrans_norms_kernel(
    const unsigned short* __restrict__ qkv, unsigned short* __restrict__ vt,
    float* __restrict__ q2g, float* __restrict__ k2g)
{
    __shared__ unsigned short Vl[64][100];
    int blk = blockIdx.x;          // bh*16 + kt
    int bh = blk >> 4, kt = blk & 15;
    int b = bh >> 3, hh = bh & 7;
    int t = threadIdx.x;
    int key = t >> 2, qc = t & 3;
    const unsigned short* tok = qkv + ((size_t)(b * S_ + kt * 64 + key)) * QKVW + hh * DH_;
    // norms: 4 threads per token, 24 q + 24 k shorts each
    float qs = 0.f, ks = 0.f;
    #pragma unroll
    for (int i = 0; i < 3; i++) {
        us8 qv = *(const us8*)(tok + (qc * 3 + i) * 8);
        us8 kv = *(const us8*)(tok + 768 + (qc * 3 + i) * 8);
        #pragma unroll
        for (int e = 0; e < 8; e++) {
            float qf = bf2f(qv[e]), kf = bf2f(kv[e]);
            qs += qf * qf; ks += kf * kf;
        }
    }
    qs += __shfl_xor(qs, 1, 4); qs += __shfl_xor(qs, 2, 4);
    ks += __shfl_xor(ks, 1, 4); ks += __shfl_xor(ks, 2, 4);
    if (qc == 0) {
        int idx = (b * H_ + hh) * S_ + kt * 64 + key;
        q2g[idx] = qs; k2g[idx] = ks * 0.25f;
    }
    // V transpose
    const unsigned short* src = tok + 1536;
    #pragma unroll
    for (int i = 0; i < 3; i++) {
        int chunk = qc + i * 4;            // 0..11, 8 shorts each
        us8 v = *(const us8*)(src + chunk * 8);
        #pragma unroll
        for (int e = 0; e < 8; e++) Vl[key][chunk * 8 + e] = v[e];
    }
    __syncthreads();
    unsigned short* dst = vt + (size_t)blk * 7168;
    #pragma unroll
    for (int r = 0; r < 3; r++) {
        int c = r * 256 + t;               // 0..767
        int vd = c >> 3, kc = c & 7;
        us8 o;
        #pragma unroll
        for (int j = 0; j < 8; j++) o[j] = Vl[kc * 8 + j][vd];
        *(us8*)(dst + vd * 72 + kc * 8) = o;
    }
}

// ---------------------------------------------------------------------------
// MFMA flash attention, L2 distances in cexp^2-scaled space: the QK MFMA with
// C-init (q2+k2) emits d2' = cexp^2*d2 directly; p = exp2(-sqrt(|d2'|)) -- no
// per-score multiply, fabs folds into the sqrt input modifier. k2 staged
// through LDS inside the double-buffered prefetch (no per-iter global stall).
// 2 q-frags/wave; K chunk-major conflict-free; XCD swizzle: one batch per XCD.
// ---------------------------------------------------------------------------
__global__ __launch_bounds__(256, 2) void attn_mfma_kernel(
    const unsigned short* __restrict__ qkv,
    const unsigned short* __restrict__ vt,
    const float* __restrict__ q2g, const float* __restrict__ k2g,
    unsigned short* __restrict__ outb)
{
    __shared__ unsigned short Klds[2][6144];     // chunk-major: [dc 0..11][key 0..63][8]
    __shared__ unsigned short Vlds[2][7168];     // [vdim][72]
    __shared__ float k2lds[2][64];               // staged k2 tile
    __shared__ unsigned short Plds[4][2][16 * 72];  // per-wave per-frag [qrow][key]

    int t = threadIdx.x;
    int lane = t & 63, w = t >> 6;
    int l16 = lane & 15, quad = lane >> 4;

    int bid = blockIdx.x;
    int slot = bid >> 3;
    int bh = (bid & 7) * 8 + (slot >> 3);
    int qt = slot & 7;
    int b = bh >> 3, hh = bh & 7;

    int qrowW = qt * 128 + w * 32;    // this wave's first q-row (32 rows, 2 frags)

    const unsigned short* qb = qkv + ((size_t)(b * S_ + qrowW)) * QKVW + hh * DH_;
    bf16x8 qf[2][3];
    #pragma unroll
    for (int f = 0; f < 2; f++)
        #pragma unroll
        for (int d = 0; d < 3; d++)
            qf[f][d] = __builtin_bit_cast(bf16x8,
                *(const i4*)(qb + (size_t)(f * 16 + l16) * QKVW + d * 32 + quad * 8));

    float q2n[2];
    #pragma unroll
    for (int f = 0; f < 2; f++)
        q2n[f] = q2g[bh * S_ + qrowW + f * 16 + l16];

    float lsum0 = 0.f, lsum1 = 0.f;
    f4 Oacc[2][6] = {};

    const unsigned short* kgb = qkv + ((size_t)(b * S_)) * QKVW + 768 + hh * DH_;
    const unsigned short* vgb0 = vt + (size_t)(bh * 16) * 7168;
    const float* k2base = k2g + bh * S_;

    int kkey = t & 63;
    #define ATTN_STAGE(bb, itv)                                                   \
        {                                                                         \
            _Pragma("unroll")                                                     \
            for (int r = 0; r < 3; r++) {                                         \
                int c = r * 256 + t;                                              \
                int dc = c >> 6;                                                  \
                GLOBAL_LOAD_LDS16(kgb + ((size_t)((itv) * 64 + kkey)) * QKVW + dc * 8, \
                                  &Klds[bb][c * 8]);                              \
            }                                                                     \
            const unsigned short* vgb = vgb0 + (size_t)(itv) * 7168;              \
            _Pragma("unroll")                                                     \
            for (int r = 0; r < 3; r++)                                           \
                GLOBAL_LOAD_LDS16(vgb + (r * 256 + t) * 8, &Vlds[bb][(r * 256 + t) * 8]); \
            if (t < 128)                                                          \
                GLOBAL_LOAD_LDS16(vgb + (768 + t) * 8, &Vlds[bb][(768 + t) * 8]); \
            if (t < 16)                                                           \
                GLOBAL_LOAD_LDS16(k2base + (itv) * 64 + t * 4, &k2lds[bb][t * 4]); \
        }

    ATTN_STAGE(0, 0);
    __syncthreads();

    for (int it = 0; it < 16; it++) {
        int cur = it & 1;
        if (it) __syncthreads();          // prev prefetch landed; prev reads done
        if (it + 1 < 16) ATTN_STAGE(cur ^ 1, it + 1);   // overlap with compute below

        // S^T = K' . Q^T + (q2+k2) : C-frag col(l16)=qrow, row(quad*4+r)=key
        const unsigned short* kB = &Klds[cur][quad * 512 + l16 * 8];
        #pragma unroll
        for (int kt2 = 0; kt2 < 4; kt2++) {
            const unsigned short* kp = kB + kt2 * 128;
            bf16x8 kf0 = __builtin_bit_cast(bf16x8, *(const i4*)(kp));
            bf16x8 kf1 = __builtin_bit_cast(bf16x8, *(const i4*)(kp + 2048));
            bf16x8 kf2 = __builtin_bit_cast(bf16x8, *(const i4*)(kp + 4096));
            f4 kk = *(const f4*)&k2lds[cur][kt2 * 16 + quad * 4];
            #pragma unroll
            for (int f = 0; f < 2; f++) {
                f4 a = {kk[0] + q2n[f], kk[1] + q2n[f], kk[2] + q2n[f], kk[3] + q2n[f]};
                __builtin_amdgcn_s_setprio(1);
                a = __builtin_amdgcn_mfma_f32_16x16x32_bf16(kf0, qf[f][0], a, 0, 0, 0);
                a = __builtin_amdgcn_mfma_f32_16x16x32_bf16(kf1, qf[f][1], a, 0, 0, 0);
                a = __builtin_amdgcn_mfma_f32_16x16x32_bf16(kf2, qf[f][2], a, 0, 0, 0);
                __builtin_amdgcn_s_setprio(0);
                #pragma unroll
                for (int r2 = 0; r2 < 4; r2++) {
                    float p = exp2f(-__builtin_amdgcn_sqrtf(__builtin_fabsf(a[r2])));
                    if (f == 0) lsum0 += p; else lsum1 += p;
                    a[r2] = p;
                }
                unsigned int plo, phi;
                asm("v_cvt_pk_bf16_f32 %0, %1, %2" : "=v"(plo) : "v"(a[0]), "v"(a[1]));
                asm("v_cvt_pk_bf16_f32 %0, %1, %2" : "=v"(phi) : "v"(a[2]), "v"(a[3]));
                uint2 pkd; pkd.x = plo; pkd.y = phi;
                *(uint2*)&Plds[w][f][l16 * 72 + kt2 * 16 + quad * 4] = pkd;
            }
        }
        // O += P . V (no rescale needed: fixed shift)
        bf16x8 pa[2][2];
        #pragma unroll
        for (int f = 0; f < 2; f++) {
            pa[f][0] = __builtin_bit_cast(bf16x8, *(const i4*)&Plds[w][f][l16 * 72 + quad * 8]);
            pa[f][1] = __builtin_bit_cast(bf16x8, *(const i4*)&Plds[w][f][l16 * 72 + 32 + quad * 8]);
        }
        __builtin_amdgcn_s_setprio(1);
        #pragma unroll
        for (int vtl = 0; vtl < 6; vtl++) {
            bf16x8 vf0 = __builtin_bit_cast(bf16x8, *(const i4*)&Vlds[cur][(vtl * 16 + l16) * 72 + quad * 8]);
            bf16x8 vf1 = __builtin_bit_cast(bf16x8, *(const i4*)&Vlds[cur][(vtl * 16 + l16) * 72 + 32 + quad * 8]);
            #pragma unroll
            for (int f = 0; f < 2; f++) {
                Oacc[f][vtl] = __builtin_amdgcn_mfma_f32_16x16x32_bf16(pa[f][0], vf0, Oacc[f][vtl], 0, 0, 0);
                Oacc[f][vtl] = __builtin_amdgcn_mfma_f32_16x16x32_bf16(pa[f][1], vf1, Oacc[f][vtl], 0, 0, 0);
            }
        }
        __builtin_amdgcn_s_setprio(0);
    }
    // deferred l-reduction over the 4 quads, per frag
    #pragma unroll
    for (int f = 0; f < 2; f++) {
        float ls = (f == 0) ? lsum0 : lsum1;
        ls += __shfl_xor(ls, 16, 64);
        ls += __shfl_xor(ls, 32, 64);
        float inv_l = 1.f / ls;
        f4 iv;
        #pragma unroll
        for (int r2 = 0; r2 < 4; r2++)
            iv[r2] = __shfl(inv_l, quad * 4 + r2, 64);
        #pragma unroll
        for (int vtl = 0; vtl < 6; vtl++)
            #pragma unroll
            for (int r2 = 0; r2 < 4; r2++) {
                int row = b * S_ + qrowW + f * 16 + quad * 4 + r2;
                outb[(size_t)row * D_ + hh * DH_ + vtl * 16 + l16] = f2bf(Oacc[f][vtl][r2] * iv[r2]);
            }
    }
    #undef ATTN_STAGE
}

// ---------------------------------------------------------------------------
extern "C" void kernel_launch(void* const* d_in, const int* in_sizes, int n_in,
                              void* d_out, int out_size, void* d_ws, size_t ws_size,
                              hipStream_t stream)
{
    const float* h    = (const float*)d_in[0];
    const float* x    = (const float*)d_in[1];
    const float* g1   = (const float*)d_in[2];
    const float* be1  = (const float*)d_in[3];
    const float* ln1w = (const float*)d_in[4];
    const float* ln1b = (const float*)d_in[5];
    const float* g2   = (const float*)d_in[6];
    const float* be2  = (const float*)d_in[7];
    const float* ln2w = (const float*)d_in[8];
    const float* ln2b = (const float*)d_in[9];
    const float* Wq   = (const float*)d_in[10];
    const float* bq   = (const float*)d_in[11];
    const float* Wk   = (const float*)d_in[12];
    const float* bk   = (const float*)d_in[13];
    const float* Wv   = (const float*)d_in[14];
    const float* bv   = (const float*)d_in[15];
    const float* Wo   = (const float*)d_in[16];
    const float* bo   = (const float*)d_in[17];
    const float* W1   = (const float*)d_in[18];
    const float* b1   = (const float*)d_in[19];
    const float* W2   = (const float*)d_in[20];
    const float* b2   = (const float*)d_in[21];

    float* out = (float*)d_out;
    char* wsb = (char*)d_ws;
    const size_t ND = (size_t)NTOK * D_;

    size_t off = 0;
    unsigned short* W1t = (unsigned short*)(wsb + off); off += 4718592;       // [3072][768]
    unsigned short* W2t = (unsigned short*)(wsb + off); off += 4718592;       // [768][3072]
    float* bqkv = (float*)(wsb + off);                  off += 16384;
    float* htmp = (float*)(wsb + off);                  off += ND * 4;        // fp32
    float* q2g  = (float*)(wsb + off);                  off += (size_t)B_ * H_ * S_ * 4;
    float* k2g  = (float*)(wsb + off);                  off += (size_t)B_ * H_ * S_ * 4;
    unsigned short* h2b = (unsigned short*)(wsb + off); off += ND * 2;        // SLN2 out
    // ---- dead pool (all dead before the MLP) ----
    size_t pool0 = off;
    unsigned short* Wqkvt = (unsigned short*)(wsb + off); off += 3538944;     // [2304][768]
    unsigned short* Wot   = (unsigned short*)(wsb + off); off += 1179648;     // [768][768]
    unsigned short* h1b   = (unsigned short*)(wsb + off); off += ND * 2;      // alias: attnb
    unsigned short* vtg   = (unsigned short*)(wsb + off); off += (size_t)1024 * 14336;
    unsigned short* qkvb  = (unsigned short*)(wsb + off); off += (size_t)NTOK * QKVW * 2;
    unsigned short* attnb   = h1b;
    unsigned short* hiddenb = (unsigned short*)(wsb + pool0);  // [8192][3072] bf16 overlay

    // --- weight prep: single merged kernel (6 transposes + bias concat) ---
    prep_all_kernel<<<6921, dim3(32, 8), 0, stream>>>(
        Wq, Wk, Wv, Wo, W1, W2, bq, bk, bv, Wqkvt, Wot, W1t, W2t, bqkv);

    // 1. SLN1 -> h1b (bf16), copy x -> out[0:ND]
    sln_kernel<<<NTOK, 192, 0, stream>>>(h, x, g1, be1, ln1w, ln1b, h1b, out);

    // 2. fused QKV GEMM: [8192,768] @ [768,2304] -> qkvb bf16 (q,k parts pre-scaled)
    gemm_mfma_kernel<1, 0><<<dim3(NTOK/128, QKVW/128), 256, 0, stream>>>(
        h1b, Wqkvt, bqkv, nullptr, qkvb, NTOK, QKVW, D_);

    // 3. V transpose tiles + q2/k2 norms (fused)
    vtrans_norms_kernel<<<1024, 256, 0, stream>>>(qkvb, vtg, q2g, k2g);

    // 4. MFMA attention -> attnb bf16 (512 blocks: 64 bh x 8 q-tiles of 128)
    attn_mfma_kernel<<<512, 256, 0, stream>>>(qkvb, vtg, q2g, k2g, attnb);

    // 5. Wo projection + residual h -> htmp fp32 (128x64 tiles: 768 blocks)
    gemm_mfma_n64_kernel<0, 0><<<dim3(NTOK/128, D_/64), 256, 0, stream>>>(
        attnb, Wot, bo, h, htmp, NTOK, D_, D_);

    // 6. SLN2 -> h2b bf16
    sln_kernel<<<NTOK, 192, 0, stream>>>(htmp, x, g2, be2, ln2w, ln2b, h2b, nullptr);

    // 7. MLP: W1 back on 128x128 tiles (R5's 256x128 regressed: 545 vs 608 TF,
    //    VGPR-capped 2 blocks/CU vs 768-grid's 3/CU need -> ragged tail)
    gemm_mfma_kernel<1, 1><<<dim3(NTOK/128, DFF_/128), 256, 0, stream>>>(
        h2b, W1t, b1, nullptr, hiddenb, NTOK, DFF_, D_);
    gemm_mfma_n64_kernel<0, 0><<<dim3(NTOK/128, D_/64), 256, 0, stream>>>(
        hiddenb, W2t, b2, htmp, out + ND, NTOK, D_, DFF_);

    (void)in_sizes; (void)n_in; (void)out_size; (void)ws_size;
}